// Round 7
// baseline (266.380 us; speedup 1.0000x reference)
//
#include <hip/hip_runtime.h>
#include <hip/hip_fp16.h>
#include <hip/hip_fp8.h>
#include <math.h>

#define NN 40000      // nodes
#define NE 640000     // raw edges
#define ET 680000     // edges + self loops
#define CH 128
#define OC 16
#define NG 64
#define NQ (ET/4)     // 170000 edge quads
#define CAP 48        // padded-CSR capacity per node (deg ~ Poisson(17))
#define NFILLB 665    // one block per 256 quads (unbucketed single pass)
#define NGEMMB 625    // 64-row tiles (full 128 cols internal)
#define NBLK1 (2*NGEMMB + (NFILLB - NGEMMB))   // 1290: pairwise interleave + tail
#define NSPLIT 20000  // gcn-out row split (pool block boundary: 20000/80=250)

typedef _Float16 h8 __attribute__((ext_vector_type(8)));
typedef float    f4 __attribute__((ext_vector_type(4)));

__device__ __forceinline__ float2 fp8x2_to_f32(unsigned short v) {
    __hip_fp8_e4m3 a, b;
    a.__x = (__hip_fp8_storage_t)(v & 0xff);
    b.__x = (__hip_fp8_storage_t)(v >> 8);
    return make_float2((float)a, (float)b);
}
__device__ __forceinline__ unsigned char f32_to_fp8(float f) {
    __hip_fp8_e4m3 t(f);
    return (unsigned char)t.__x;
}

// ---- prep: zero scratch + graph bounds + W->fp16 transposed + Wg folding --
// Layer-3 algebra: gather/pool/Wg commute (all linear), so Wg is folded into
// the head: Wgf = Wg@Wfc [128x16], bgf = bg@Wfc + bfc [16]. gemm_k3 deleted.
__global__ __launch_bounds__(256)
void prep(const int* __restrict__ batch, int* __restrict__ gstart,
          int* __restrict__ cur_d, int* __restrict__ cur_s,
          float* __restrict__ pooled,
          const float* __restrict__ W1, const float* __restrict__ W2,
          const float* __restrict__ Wg, const float* __restrict__ Wfc,
          const float* __restrict__ bg, const float* __restrict__ bfc,
          _Float16* __restrict__ Wt1, _Float16* __restrict__ Wt2,
          float* __restrict__ Wgf, float* __restrict__ bgf)
{
    int i = blockIdx.x * 256 + threadIdx.x;
    if (i < NN) {
        cur_d[i] = 0; cur_s[i] = 0;
        int b = batch[i];
        if (i == 0) { for (int g = 0; g <= b; ++g) gstart[g] = 0; }
        else { int pb = batch[i - 1]; for (int g = pb + 1; g <= b; ++g) gstart[g] = i; }
        if (i == NN - 1) { for (int g = b + 1; g <= NG; ++g) gstart[g] = NN; }
    }
    if (i < NG * CH) pooled[i] = 0.f;
    if (i < CH * CH) {
        int k = i >> 7, n = i & 127;          // coalesced read W[k][n]
        Wt1[n * CH + k] = (_Float16)W1[i];
        Wt2[n * CH + k] = (_Float16)W2[i];
    }
    if (i < CH * OC) {                        // Wgf[k][o] = sum_c Wg[k][c]*Wfc[c][o]
        int k = i >> 4, o = i & 15;
        float acc = 0.f;
        for (int c = 0; c < CH; ++c)
            acc += Wg[k * CH + c] * Wfc[c * OC + o];
        Wgf[k * OC + o] = acc;
    }
    if (i >= CH * OC && i < CH * OC + OC) {   // bgf[o] = sum_c bg[c]*Wfc[c][o] + bfc[o]
        int o = i - CH * OC;
        float acc = bfc[o];
        for (int c = 0; c < CH; ++c)
            acc += bg[c] * Wfc[c * OC + o];
        bgf[o] = acc;
    }
}

// ---- stage Wt (global, [n][k] row-major) into LDS wt[128][136] ------------
__device__ __forceinline__
void stage_w(_Float16 (*wt)[136], const _Float16* __restrict__ Wt, int tid)
{
#pragma unroll
    for (int i = 0; i < 8; ++i) {
        int f = tid + i * 256;            // 0..2047 half8 chunks
        int n = f >> 4, c8 = f & 15;
        *(float4*)&wt[n][c8 * 8] = *(const float4*)(Wt + (size_t)n * CH + c8 * 8);
    }
}

// ---- MFMA body: 64 rows x 128 cols, K=128; xs and wt staged in LDS --------
// A-frag A[m][k=quad*8+j]; C/D col=lane&15, row=quad*4+reg (verified R6).
// b128 LDS reads process 16 lanes/phase -> (m,quad) mapping is 2-way/phase,
// conflict-free. Full row per block -> s[row] is a plain store (no atomic).
template<bool BIAS, bool ATTN>
__device__ __forceinline__
void mfma_body(_Float16 (*xs)[136], _Float16 (*wt)[136],
               const float* __restrict__ bias, const float* __restrict__ att,
               unsigned char* __restrict__ out8, float* __restrict__ s,
               int rb, int tid)
{
    const int wv = tid >> 6, lane = tid & 63;
    const int m = lane & 15, quad = lane >> 4;
    f4 acc[8] = {};
#pragma unroll
    for (int ks = 0; ks < 4; ++ks) {
        h8 a = *(const h8*)&xs[wv * 16 + m][ks * 32 + quad * 8];
#pragma unroll
        for (int t = 0; t < 8; ++t) {
            h8 b = *(const h8*)&wt[t * 16 + m][ks * 32 + quad * 8];
            acc[t] = __builtin_amdgcn_mfma_f32_16x16x32_f16(a, b, acc[t], 0, 0, 0);
        }
    }
    float pr[4] = {0.f, 0.f, 0.f, 0.f};
#pragma unroll
    for (int t = 0; t < 8; ++t) {
        int col = t * 16 + m;
        float bv = BIAS ? bias[col] : 0.f;
        float av = ATTN ? att[col] : 0.f;
#pragma unroll
        for (int r = 0; r < 4; ++r) {
            float o = acc[t][r] + bv;
            int row = rb + wv * 16 + quad * 4 + r;
            out8[(size_t)row * CH + col] = f32_to_fp8(o);
            if (ATTN) pr[r] += o * av;
        }
    }
    if (ATTN) {
#pragma unroll
        for (int r = 0; r < 4; ++r) {
            float p = pr[r];
            p += __shfl_xor(p, 1); p += __shfl_xor(p, 2);
            p += __shfl_xor(p, 4); p += __shfl_xor(p, 8);
            if (m == 0) s[rb + wv * 16 + quad * 4 + r] = p;  // full row here
        }
    }
}

// ---- fill body: unbucketed padded-CSR fill, 4 edges/thread, both sides ----
__device__ __forceinline__
void fill_body(int fb, int tid, const int* __restrict__ ei,
               int* __restrict__ cur_d, int* __restrict__ cur_s,
               unsigned short* __restrict__ pad_src,
               unsigned short* __restrict__ pad_dst)
{
    int q = fb * 256 + tid;
    if (q >= NQ) return;
    int e0 = q * 4;
    int4 sv, dv;
    if (e0 < NE) {                          // quads never straddle NE (NE%4==0)
        sv = *(const int4*)(ei + e0);
        dv = *(const int4*)(ei + NE + e0);
    } else {
        int b = e0 - NE;
        sv = make_int4(b, b + 1, b + 2, b + 3);
        dv = sv;
    }
    const int* sc = (const int*)&sv;
    const int* dc = (const int*)&dv;
#pragma unroll
    for (int u = 0; u < 4; ++u) {
        int srcE = sc[u], dstE = dc[u];
        int p = atomicAdd(cur_d + dstE, 1);
        if (p < CAP) pad_src[dstE * CAP + p] = (unsigned short)srcE;
        int p2 = atomicAdd(cur_s + srcE, 1);
        if (p2 < CAP) pad_dst[srcE * CAP + p2] = (unsigned short)dstE;
    }
}

// ---- fused gemm1 + fill, pairwise-interleaved for co-residency ------------
__global__ __launch_bounds__(256)
void fill_gemm1(const float* __restrict__ x, const _Float16* __restrict__ Wt1,
                const float* __restrict__ b1, const float* __restrict__ att1,
                unsigned char* __restrict__ out8, float* __restrict__ s1,
                const int* __restrict__ ei, int* __restrict__ cur_d,
                int* __restrict__ cur_s, unsigned short* __restrict__ pad_src,
                unsigned short* __restrict__ pad_dst)
{
    __shared__ __attribute__((aligned(16))) _Float16 xs[64][136];
    __shared__ __attribute__((aligned(16))) _Float16 wt[128][136];
    int bid = blockIdx.x;
    if (bid < 2 * NGEMMB && (bid & 1) == 0) {
        int g = bid >> 1;
        int rb = g * 64, tid = threadIdx.x;
#pragma unroll
        for (int i = 0; i < 4; ++i) {
            int f = tid + i * 256;
            int r = f >> 4, c8 = f & 15;
            const float* p = x + (size_t)(rb + r) * CH + c8 * 8;
            float4 v0 = *(const float4*)p;
            float4 v1 = *(const float4*)(p + 4);
            __half2 h[4] = { __floats2half2_rn(v0.x, v0.y), __floats2half2_rn(v0.z, v0.w),
                             __floats2half2_rn(v1.x, v1.y), __floats2half2_rn(v1.z, v1.w) };
            *(float4*)&xs[r][c8 * 8] = *(float4*)h;
        }
        stage_w(wt, Wt1, tid);
        __syncthreads();
        mfma_body<true, true>(xs, wt, b1, att1, out8, s1, rb, tid);
        return;
    }
    int fb = (bid < 2 * NGEMMB) ? (bid >> 1) : (NGEMMB + (bid - 2 * NGEMMB));
    if (fb < NFILLB)
        fill_body(fb, threadIdx.x, ei, cur_d, cur_s, pad_src, pad_dst);
}

// ---- standalone gemm (layer 2): stage fp16 input + W, run MFMA ------------
template<bool RELU, bool BIAS, bool ATTN>
__global__ __launch_bounds__(256)
void gemm_k(const __half* __restrict__ in, const _Float16* __restrict__ Wt,
            const float* __restrict__ bias, const float* __restrict__ att,
            unsigned char* __restrict__ out8, float* __restrict__ s)
{
    __shared__ __attribute__((aligned(16))) _Float16 xs[64][136];
    __shared__ __attribute__((aligned(16))) _Float16 wt[128][136];
    const int tid = threadIdx.x;
    const int rb = blockIdx.x * 64;
#pragma unroll
    for (int i = 0; i < 4; ++i) {
        int f = tid + i * 256;            // 0..1023 half8 chunks
        int r = f >> 4, c8 = f & 15;
        float4 raw = *(const float4*)(in + (size_t)(rb + r) * CH + c8 * 8);
        if (RELU) {
            __half2* h2 = (__half2*)&raw;
#pragma unroll
            for (int u = 0; u < 4; ++u) {
                float2 fv = __half22float2(h2[u]);
                h2[u] = __floats2half2_rn(fmaxf(fv.x, 0.f), fmaxf(fv.y, 0.f));
            }
        }
        *(float4*)&xs[r][c8 * 8] = raw;
    }
    stage_w(wt, Wt, tid);
    __syncthreads();
    mfma_body<BIAS, ATTN>(xs, wt, bias, att, out8, s, rb, tid);
}

// ------- per-src-node softmax denom (no max-sub; |t|<~20 safe in fp32) -----
__global__ __launch_bounds__(256)
void softmax_stats(const int* __restrict__ cur_s,
                   const unsigned short* __restrict__ pad_dst,
                   const float* __restrict__ s, float* __restrict__ ssum)
{
    int node = (blockIdx.x * 256 + threadIdx.x) >> 6;
    int lane = threadIdx.x & 63;
    if (node >= NN) return;
    int deg = min(cur_s[node], CAP);
    float si = s[node];
    float sum = 0.f;
    if (lane < deg) {
        int d = pad_dst[node * CAP + lane];
        float t = si + s[d];
        t = t > 0.f ? t : 0.2f * t;
        sum = expf(t);
    }
#pragma unroll
    for (int o = 32; o; o >>= 1) sum += __shfl_xor(sum, o);
    if (lane == 0) ssum[node] = sum;
}

// ------- gather core: LOAD-BURST version -----------------------------------
// deg is wave-uniform (one node per wave), so all row loads for the node are
// issued in one burst (j=0..11, e=4j+qtr) BEFORE any decode: the scattered-
// row latency (~600cy L2/L3) is paid once per node, not once per 8-edge
// iteration. v[12]+wj[12] cost ~36 VGPR; all indexing compile-time (rule #20).
// OM=0: fp16 row out. OM=1: relu + fp8 row out (feeds the layer-3 gather).
template<int OM>
__device__ __forceinline__
void gather_core(int node, int lane, int deg, int src, float w,
                 const unsigned char* __restrict__ h8p, void* __restrict__ outrow)
{
    int qtr = lane >> 4, cl = lane & 15;
    int nj = 2 * ((deg + 7) >> 3);        // 0..12, wave-uniform
    uint2 v[12]; float wj[12];
#pragma unroll
    for (int j = 0; j < 12; ++j) {        // phase 1: broadcast + issue loads
        if (j < nj) {
            int e = 4 * j + qtr;          // e <= 47 < 64
            int sj = __shfl(src, e);
            wj[j]  = __shfl(w, e);
            v[j] = ((const uint2*)(h8p + (size_t)sj * CH))[cl];
        }
    }
    float a[8] = {};
#pragma unroll
    for (int j = 0; j < 12; ++j) {        // phase 2: decode + accumulate
        if (j < nj) {
            float2 p0 = fp8x2_to_f32((unsigned short)(v[j].x & 0xffff));
            float2 p1 = fp8x2_to_f32((unsigned short)(v[j].x >> 16));
            float2 p2 = fp8x2_to_f32((unsigned short)(v[j].y & 0xffff));
            float2 p3 = fp8x2_to_f32((unsigned short)(v[j].y >> 16));
            float ww = wj[j];
            a[0] += p0.x * ww; a[1] += p0.y * ww;
            a[2] += p1.x * ww; a[3] += p1.y * ww;
            a[4] += p2.x * ww; a[5] += p2.y * ww;
            a[6] += p3.x * ww; a[7] += p3.y * ww;
        }
    }
#pragma unroll
    for (int k = 0; k < 8; ++k) {
        a[k] += __shfl_xor(a[k], 16);
        a[k] += __shfl_xor(a[k], 32);
    }
    if (qtr == 0) {
        if (OM == 0) {
            float4 st;
            ((__half2*)&st)[0] = __floats2half2_rn(a[0], a[1]);
            ((__half2*)&st)[1] = __floats2half2_rn(a[2], a[3]);
            ((__half2*)&st)[2] = __floats2half2_rn(a[4], a[5]);
            ((__half2*)&st)[3] = __floats2half2_rn(a[6], a[7]);
            ((float4*)outrow)[cl] = st;
        } else {
            unsigned lo = (unsigned)f32_to_fp8(fmaxf(a[0], 0.f))
                        | ((unsigned)f32_to_fp8(fmaxf(a[1], 0.f)) << 8)
                        | ((unsigned)f32_to_fp8(fmaxf(a[2], 0.f)) << 16)
                        | ((unsigned)f32_to_fp8(fmaxf(a[3], 0.f)) << 24);
            unsigned hi = (unsigned)f32_to_fp8(fmaxf(a[4], 0.f))
                        | ((unsigned)f32_to_fp8(fmaxf(a[5], 0.f)) << 8)
                        | ((unsigned)f32_to_fp8(fmaxf(a[6], 0.f)) << 16)
                        | ((unsigned)f32_to_fp8(fmaxf(a[7], 0.f)) << 24);
            ((uint2*)outrow)[cl] = make_uint2(lo, hi);
        }
    }
}

// ------- GT aggregation ----------------------------------------------------
// F8OUT=false (layer 1): fp16 out for gemm_k2. F8OUT=true (layer 2): relu'd
// fp8 out, consumed directly by gcn_gather (layer-3 gemm eliminated).
template<bool F8OUT>
__global__ __launch_bounds__(256)
void gt_gather(const int* __restrict__ cur_d,
               const unsigned short* __restrict__ pad_src,
               const unsigned char* __restrict__ h8p, const float* __restrict__ s,
               const float* __restrict__ ssum, __half* __restrict__ out16,
               unsigned char* __restrict__ o8)
{
    int node = (blockIdx.x * 256 + threadIdx.x) >> 6;
    int lane = threadIdx.x & 63;
    if (node >= NN) return;
    int deg = min(cur_d[node], CAP);
    float sd = s[node];
    int src = 0; float w = 0.f;
    if (lane < deg) {
        src = pad_src[node * CAP + lane];
        float t = sd + s[src];
        t = t > 0.f ? t : 0.2f * t;
        w = expf(t) / ssum[src];
    }
    if (F8OUT)
        gather_core<1>(node, lane, deg, src, w, h8p, o8 + (size_t)node * CH);
    else
        gather_core<0>(node, lane, deg, src, w, h8p, out16 + (size_t)node * CH);
}

// ------- GCN aggregation, inline dinv; split fp16 output (buffer reuse) ----
__global__ __launch_bounds__(256)
void gcn_gather(const int* __restrict__ cur_d,
                const unsigned short* __restrict__ pad_src,
                const unsigned char* __restrict__ h8p,
                __half* __restrict__ outA, __half* __restrict__ outB)
{
    int node = (blockIdx.x * 256 + threadIdx.x) >> 6;
    int lane = threadIdx.x & 63;
    if (node >= NN) return;
    int dn = cur_d[node];
    int deg = min(dn, CAP);
    float nu = rsqrtf((float)max(dn, 1));
    int src = 0; float w = 0.f;
    if (lane < deg) {
        src = pad_src[node * CAP + lane];
        w = rsqrtf((float)max(cur_d[src], 1)) * nu;
    }
    __half* row = (node < NSPLIT) ? outA + (size_t)node * CH
                                  : outB + (size_t)(node - NSPLIT) * CH;
    gather_core<0>(node, lane, deg, src, w, h8p, row);
}

// ---- pooling: 8-deep batched loads; boundary branch is block-uniform ------
// Input rows split: [0,20000) in hA, [20000,40000) in hB; 500 blocks x 80
// rows -> block 250 starts exactly at the split (no straddle).
__global__ __launch_bounds__(128)
void pool_part(const __half* __restrict__ hA, const __half* __restrict__ hB,
               const int* __restrict__ batch, float* __restrict__ pooled)
{
    int ch = threadIdx.x;
    int start = blockIdx.x * 80;
    const __half* hp = (start < NSPLIT) ? hA + (size_t)start * CH
                                        : hB + (size_t)(start - NSPLIT) * CH;
    float acc = 0.f;
    int curg = batch[start];
    for (int base = start; base < start + 80; base += 8) {
        float vals[8]; int gs[8];
#pragma unroll
        for (int u = 0; u < 8; ++u)
            vals[u] = __half2float(hp[(size_t)(base - start + u) * CH + ch]);
#pragma unroll
        for (int u = 0; u < 8; ++u) gs[u] = batch[base + u];
#pragma unroll
        for (int u = 0; u < 8; ++u) {
            if (gs[u] != curg) {
                atomicAdd(pooled + (size_t)curg * CH + ch, acc);
                acc = 0.f; curg = gs[u];
            }
            acc += vals[u];
        }
    }
    atomicAdd(pooled + (size_t)curg * CH + ch, acc);
}

// ---- head: logits = (psum/cnt) @ Wgf + bgf; log_softmax -------------------
__global__ __launch_bounds__(256)
void head_kernel(const float* __restrict__ psum, const int* __restrict__ gstart,
                 const float* __restrict__ Wgf, const float* __restrict__ bgf,
                 float* __restrict__ out)
{
    __shared__ float lg[NG][OC];
    int tid = threadIdx.x;
#pragma unroll
    for (int i = 0; i < 4; ++i) {
        int f = tid + i * 256;        // 0..1023
        int g = f >> 4, o = f & 15;
        float cnt = fmaxf((float)(gstart[g + 1] - gstart[g]), 1.0f);
        float inv = 1.0f / cnt;
        float acc = bgf[o];
        for (int c = 0; c < CH; ++c)
            acc += psum[g * CH + c] * inv * Wgf[c * OC + o];
        lg[g][o] = acc;
    }
    __syncthreads();
    if (tid < NG) {
        float m = -1e30f;
#pragma unroll
        for (int o = 0; o < OC; ++o) m = fmaxf(m, lg[tid][o]);
        float sum = 0.f;
#pragma unroll
        for (int o = 0; o < OC; ++o) sum += expf(lg[tid][o] - m);
        float lse = m + logf(sum);
#pragma unroll
        for (int o = 0; o < OC; ++o) out[tid * OC + o] = lg[tid][o] - lse;
    }
}

extern "C" void kernel_launch(void* const* d_in, const int* in_sizes, int n_in,
                              void* d_out, int out_size, void* d_ws, size_t ws_size,
                              hipStream_t stream)
{
    const float* x     = (const float*)d_in[0];
    const int*   ei    = (const int*)d_in[1];
    const int*   batch = (const int*)d_in[2];
    const float* W1    = (const float*)d_in[3];
    const float* b1    = (const float*)d_in[4];
    const float* att1  = (const float*)d_in[5];
    const float* W2    = (const float*)d_in[6];
    const float* b2    = (const float*)d_in[7];
    const float* att2  = (const float*)d_in[8];
    const float* Wg    = (const float*)d_in[9];
    const float* bg    = (const float*)d_in[10];
    const float* Wfc   = (const float*)d_in[11];
    const float* bfc   = (const float*)d_in[12];
    float* out = (float*)d_out;

    const size_t NNCH = (size_t)NN * CH;
    __half* B16 = (__half*)d_ws;                       // [NN*CH] fp16 scratch
    unsigned char* A8 = (unsigned char*)(B16 + NNCH);  // [NN*CH] fp8 scratch
    // Layer-3 buffer reuse (x2 and h2 are dead at the point of each reuse):
    unsigned char* G8 = (unsigned char*)B16;           // relu(x3) fp8, 5.12 MB
    __half* GO_A = B16 + (size_t)NSPLIT * CH;          // gcn out rows 0..19999
    __half* GO_B = (__half*)A8;                        // gcn out rows 20000..39999
    _Float16* Wt1 = (_Float16*)(A8 + NNCH);            // [CH*CH]
    _Float16* Wt2 = Wt1 + CH * CH;
    float* Wgf    = (float*)(Wt2 + CH * CH);           // [CH*OC]
    float* bgf    = Wgf + CH * OC;                     // [OC]
    int*   cur_d  = (int*)(bgf + OC);                  // [NN]
    int*   cur_s  = cur_d + NN;                        // [NN]
    float* s1     = (float*)(cur_s + NN);              // [NN]
    float* s2     = s1 + NN;                           // [NN]
    float* ssum   = s2 + NN;                           // [NN]
    float* pooled = ssum + NN;                         // [NG*CH]
    int*   gstart = (int*)(pooled + NG * CH);          // [NG+1]
    unsigned short* pad_src = (unsigned short*)(gstart + NG + 1);  // [NN*CAP]
    unsigned short* pad_dst = pad_src + (size_t)NN * CAP;          // [NN*CAP]

    const int WB = NN / 4;                 // 10000 (wave-per-node grids)

    prep<<<157, 256, 0, stream>>>(batch, gstart, cur_d, cur_s, pooled,
                                  W1, W2, Wg, Wfc, bg, bfc, Wt1, Wt2, Wgf, bgf);

    // ---- GT layer 1: gemm1 co-resident with CSR fill ----------------------
    fill_gemm1<<<NBLK1, 256, 0, stream>>>(
        x, Wt1, b1, att1, A8, s1, ei, cur_d, cur_s, pad_src, pad_dst);
    softmax_stats<<<WB, 256, 0, stream>>>(cur_s, pad_dst, s1, ssum);
    gt_gather<false><<<WB, 256, 0, stream>>>(cur_d, pad_src, A8, s1, ssum,
                                             B16, nullptr);

    // ---- GT layer 2 (relu folded into gemm input read) --------------------
    gemm_k<true, true, true><<<NGEMMB, 256, 0, stream>>>(
        B16, Wt2, b2, att2, A8, s2);
    softmax_stats<<<WB, 256, 0, stream>>>(cur_s, pad_dst, s2, ssum);
    gt_gather<true><<<WB, 256, 0, stream>>>(cur_d, pad_src, A8, s2, ssum,
                                            nullptr, G8);

    // ---- GCN layer: gather only (Wg folded into head via Wgf) -------------
    gcn_gather<<<WB, 256, 0, stream>>>(cur_d, pad_src, G8, GO_A, GO_B);

    // ---- pool + head ------------------------------------------------------
    pool_part<<<500, 128, 0, stream>>>(GO_A, GO_B, batch, pooled);
    head_kernel<<<1, 256, 0, stream>>>(pooled, gstart, Wgf, bgf, out);
}

// Round 8
// 260.555 us; speedup vs baseline: 1.0224x; 1.0224x over previous
//
#include <hip/hip_runtime.h>
#include <hip/hip_fp16.h>
#include <hip/hip_fp8.h>
#include <math.h>

#define NN 40000      // nodes
#define NE 640000     // raw edges
#define ET 680000     // edges + self loops
#define CH 128
#define OC 16
#define NG 64
#define NQ (ET/4)     // 170000 edge quads
#define CAP 48        // padded-CSR capacity per node (deg ~ Poisson(17))
#define NFILLB 665    // one block per 256 quads (unbucketed single pass)
#define NGEMMB 625    // 64-row tiles (full 128 cols internal)
#define NBLK1 (2*NGEMMB + (NFILLB - NGEMMB))   // 1290: pairwise interleave + tail
#define NSPLIT 20000  // gcn-out row split (pool block boundary: 20000/80=250)

typedef _Float16 h8 __attribute__((ext_vector_type(8)));
typedef float    f4 __attribute__((ext_vector_type(4)));
typedef float    f2 __attribute__((ext_vector_type(2)));

// ---- fp8 e4m3 conversions: HARDWARE path (v_cvt_pk_*_fp8, OCP on gfx950) --
// The HIP header's __hip_fp8_e4m3 OCP conversion may be a software bit-manip
// routine; gathers do ~48 decodes/lane and gemm epilogues 32 encodes/thread,
// so a software path makes those kernels VALU-bound. Guarded fallback keeps
// compile safety; numerics are RNE in both paths (values << e4m3 saturation).
#if __has_builtin(__builtin_amdgcn_cvt_pk_f32_fp8) && __has_builtin(__builtin_amdgcn_cvt_pk_fp8_f32)
#define FP8_HW 1
#else
#define FP8_HW 0
#endif

__device__ __forceinline__ float2 fp8x2_to_f32_sw(unsigned short v) {
    __hip_fp8_e4m3 a, b;
    a.__x = (__hip_fp8_storage_t)(v & 0xff);
    b.__x = (__hip_fp8_storage_t)(v >> 8);
    return make_float2((float)a, (float)b);
}

__device__ __forceinline__ unsigned char f32_to_fp8(float f) {
#if FP8_HW
    return (unsigned char)(__builtin_amdgcn_cvt_pk_fp8_f32(f, f, 0, false) & 0xff);
#else
    __hip_fp8_e4m3 t(f);
    return (unsigned char)t.__x;
#endif
}

// decode 8 fp8 bytes (uint2) and accumulate a[k] += val[k]*w
__device__ __forceinline__ void decode_fma8(uint2 v, float w, float* a) {
#if FP8_HW
    f2 p0 = __builtin_amdgcn_cvt_pk_f32_fp8((int)v.x, false);
    f2 p1 = __builtin_amdgcn_cvt_pk_f32_fp8((int)v.x, true);
    f2 p2 = __builtin_amdgcn_cvt_pk_f32_fp8((int)v.y, false);
    f2 p3 = __builtin_amdgcn_cvt_pk_f32_fp8((int)v.y, true);
    a[0] += p0[0] * w; a[1] += p0[1] * w;
    a[2] += p1[0] * w; a[3] += p1[1] * w;
    a[4] += p2[0] * w; a[5] += p2[1] * w;
    a[6] += p3[0] * w; a[7] += p3[1] * w;
#else
    float2 p0 = fp8x2_to_f32_sw((unsigned short)(v.x & 0xffff));
    float2 p1 = fp8x2_to_f32_sw((unsigned short)(v.x >> 16));
    float2 p2 = fp8x2_to_f32_sw((unsigned short)(v.y & 0xffff));
    float2 p3 = fp8x2_to_f32_sw((unsigned short)(v.y >> 16));
    a[0] += p0.x * w; a[1] += p0.y * w;
    a[2] += p1.x * w; a[3] += p1.y * w;
    a[4] += p2.x * w; a[5] += p2.y * w;
    a[6] += p3.x * w; a[7] += p3.y * w;
#endif
}

// pack 4 f32 (relu'd) into 4 fp8 bytes of a uint
__device__ __forceinline__ unsigned pack_fp8x4_relu(float a0, float a1,
                                                    float a2, float a3) {
#if FP8_HW
    int w = __builtin_amdgcn_cvt_pk_fp8_f32(fmaxf(a0, 0.f), fmaxf(a1, 0.f), 0, false);
    w = __builtin_amdgcn_cvt_pk_fp8_f32(fmaxf(a2, 0.f), fmaxf(a3, 0.f), w, true);
    return (unsigned)w;
#else
    return (unsigned)f32_to_fp8(fmaxf(a0, 0.f))
         | ((unsigned)f32_to_fp8(fmaxf(a1, 0.f)) << 8)
         | ((unsigned)f32_to_fp8(fmaxf(a2, 0.f)) << 16)
         | ((unsigned)f32_to_fp8(fmaxf(a3, 0.f)) << 24);
#endif
}

// ---- prep: zero scratch + graph bounds + W->fp16 transposed + Wg folding --
// Layer-3 algebra: gather/pool/Wg commute (all linear), so Wg is folded into
// the head: Wgf = Wg@Wfc [128x16], bgf = bg@Wfc + bfc [16]. gemm_k3 deleted.
__global__ __launch_bounds__(256)
void prep(const int* __restrict__ batch, int* __restrict__ gstart,
          int* __restrict__ cur_d, int* __restrict__ cur_s,
          float* __restrict__ pooled,
          const float* __restrict__ W1, const float* __restrict__ W2,
          const float* __restrict__ Wg, const float* __restrict__ Wfc,
          const float* __restrict__ bg, const float* __restrict__ bfc,
          _Float16* __restrict__ Wt1, _Float16* __restrict__ Wt2,
          float* __restrict__ Wgf, float* __restrict__ bgf)
{
    int i = blockIdx.x * 256 + threadIdx.x;
    if (i < NN) {
        cur_d[i] = 0; cur_s[i] = 0;
        int b = batch[i];
        if (i == 0) { for (int g = 0; g <= b; ++g) gstart[g] = 0; }
        else { int pb = batch[i - 1]; for (int g = pb + 1; g <= b; ++g) gstart[g] = i; }
        if (i == NN - 1) { for (int g = b + 1; g <= NG; ++g) gstart[g] = NN; }
    }
    if (i < NG * CH) pooled[i] = 0.f;
    if (i < CH * CH) {
        int k = i >> 7, n = i & 127;          // coalesced read W[k][n]
        Wt1[n * CH + k] = (_Float16)W1[i];
        Wt2[n * CH + k] = (_Float16)W2[i];
    }
    if (i < CH * OC) {                        // Wgf[k][o] = sum_c Wg[k][c]*Wfc[c][o]
        int k = i >> 4, o = i & 15;
        float acc = 0.f;
        for (int c = 0; c < CH; ++c)
            acc += Wg[k * CH + c] * Wfc[c * OC + o];
        Wgf[k * OC + o] = acc;
    }
    if (i >= CH * OC && i < CH * OC + OC) {   // bgf[o] = sum_c bg[c]*Wfc[c][o] + bfc[o]
        int o = i - CH * OC;
        float acc = bfc[o];
        for (int c = 0; c < CH; ++c)
            acc += bg[c] * Wfc[c * OC + o];
        bgf[o] = acc;
    }
}

// ---- stage Wt (global, [n][k] row-major) into LDS wt[128][136] ------------
__device__ __forceinline__
void stage_w(_Float16 (*wt)[136], const _Float16* __restrict__ Wt, int tid)
{
#pragma unroll
    for (int i = 0; i < 8; ++i) {
        int f = tid + i * 256;            // 0..2047 half8 chunks
        int n = f >> 4, c8 = f & 15;
        *(float4*)&wt[n][c8 * 8] = *(const float4*)(Wt + (size_t)n * CH + c8 * 8);
    }
}

// ---- MFMA body: 64 rows x 128 cols, K=128; xs and wt staged in LDS --------
// A-frag A[m][k=quad*8+j]; C/D col=lane&15, row=quad*4+reg (verified R6).
// b128 LDS reads process 16 lanes/phase -> (m,quad) mapping is 2-way/phase,
// conflict-free. Full row per block -> s[row] is a plain store (no atomic).
template<bool BIAS, bool ATTN>
__device__ __forceinline__
void mfma_body(_Float16 (*xs)[136], _Float16 (*wt)[136],
               const float* __restrict__ bias, const float* __restrict__ att,
               unsigned char* __restrict__ out8, float* __restrict__ s,
               int rb, int tid)
{
    const int wv = tid >> 6, lane = tid & 63;
    const int m = lane & 15, quad = lane >> 4;
    f4 acc[8] = {};
#pragma unroll
    for (int ks = 0; ks < 4; ++ks) {
        h8 a = *(const h8*)&xs[wv * 16 + m][ks * 32 + quad * 8];
#pragma unroll
        for (int t = 0; t < 8; ++t) {
            h8 b = *(const h8*)&wt[t * 16 + m][ks * 32 + quad * 8];
            acc[t] = __builtin_amdgcn_mfma_f32_16x16x32_f16(a, b, acc[t], 0, 0, 0);
        }
    }
    float pr[4] = {0.f, 0.f, 0.f, 0.f};
#pragma unroll
    for (int t = 0; t < 8; ++t) {
        int col = t * 16 + m;
        float bv = BIAS ? bias[col] : 0.f;
        float av = ATTN ? att[col] : 0.f;
#pragma unroll
        for (int r = 0; r < 4; ++r) {
            float o = acc[t][r] + bv;
            int row = rb + wv * 16 + quad * 4 + r;
            out8[(size_t)row * CH + col] = f32_to_fp8(o);
            if (ATTN) pr[r] += o * av;
        }
    }
    if (ATTN) {
#pragma unroll
        for (int r = 0; r < 4; ++r) {
            float p = pr[r];
            p += __shfl_xor(p, 1); p += __shfl_xor(p, 2);
            p += __shfl_xor(p, 4); p += __shfl_xor(p, 8);
            if (m == 0) s[rb + wv * 16 + quad * 4 + r] = p;  // full row here
        }
    }
}

// ---- fill body: unbucketed padded-CSR fill, 4 edges/thread, both sides ----
__device__ __forceinline__
void fill_body(int fb, int tid, const int* __restrict__ ei,
               int* __restrict__ cur_d, int* __restrict__ cur_s,
               unsigned short* __restrict__ pad_src,
               unsigned short* __restrict__ pad_dst)
{
    int q = fb * 256 + tid;
    if (q >= NQ) return;
    int e0 = q * 4;
    int4 sv, dv;
    if (e0 < NE) {                          // quads never straddle NE (NE%4==0)
        sv = *(const int4*)(ei + e0);
        dv = *(const int4*)(ei + NE + e0);
    } else {
        int b = e0 - NE;
        sv = make_int4(b, b + 1, b + 2, b + 3);
        dv = sv;
    }
    const int* sc = (const int*)&sv;
    const int* dc = (const int*)&dv;
#pragma unroll
    for (int u = 0; u < 4; ++u) {
        int srcE = sc[u], dstE = dc[u];
        int p = atomicAdd(cur_d + dstE, 1);
        if (p < CAP) pad_src[dstE * CAP + p] = (unsigned short)srcE;
        int p2 = atomicAdd(cur_s + srcE, 1);
        if (p2 < CAP) pad_dst[srcE * CAP + p2] = (unsigned short)dstE;
    }
}

// ---- fused gemm1 + fill, pairwise-interleaved for co-residency ------------
__global__ __launch_bounds__(256)
void fill_gemm1(const float* __restrict__ x, const _Float16* __restrict__ Wt1,
                const float* __restrict__ b1, const float* __restrict__ att1,
                unsigned char* __restrict__ out8, float* __restrict__ s1,
                const int* __restrict__ ei, int* __restrict__ cur_d,
                int* __restrict__ cur_s, unsigned short* __restrict__ pad_src,
                unsigned short* __restrict__ pad_dst)
{
    __shared__ __attribute__((aligned(16))) _Float16 xs[64][136];
    __shared__ __attribute__((aligned(16))) _Float16 wt[128][136];
    int bid = blockIdx.x;
    if (bid < 2 * NGEMMB && (bid & 1) == 0) {
        int g = bid >> 1;
        int rb = g * 64, tid = threadIdx.x;
#pragma unroll
        for (int i = 0; i < 4; ++i) {
            int f = tid + i * 256;
            int r = f >> 4, c8 = f & 15;
            const float* p = x + (size_t)(rb + r) * CH + c8 * 8;
            float4 v0 = *(const float4*)p;
            float4 v1 = *(const float4*)(p + 4);
            __half2 h[4] = { __floats2half2_rn(v0.x, v0.y), __floats2half2_rn(v0.z, v0.w),
                             __floats2half2_rn(v1.x, v1.y), __floats2half2_rn(v1.z, v1.w) };
            *(float4*)&xs[r][c8 * 8] = *(float4*)h;
        }
        stage_w(wt, Wt1, tid);
        __syncthreads();
        mfma_body<true, true>(xs, wt, b1, att1, out8, s1, rb, tid);
        return;
    }
    int fb = (bid < 2 * NGEMMB) ? (bid >> 1) : (NGEMMB + (bid - 2 * NGEMMB));
    if (fb < NFILLB)
        fill_body(fb, threadIdx.x, ei, cur_d, cur_s, pad_src, pad_dst);
}

// ---- standalone gemm (layer 2): stage fp16 input + W, run MFMA ------------
template<bool RELU, bool BIAS, bool ATTN>
__global__ __launch_bounds__(256)
void gemm_k(const __half* __restrict__ in, const _Float16* __restrict__ Wt,
            const float* __restrict__ bias, const float* __restrict__ att,
            unsigned char* __restrict__ out8, float* __restrict__ s)
{
    __shared__ __attribute__((aligned(16))) _Float16 xs[64][136];
    __shared__ __attribute__((aligned(16))) _Float16 wt[128][136];
    const int tid = threadIdx.x;
    const int rb = blockIdx.x * 64;
#pragma unroll
    for (int i = 0; i < 4; ++i) {
        int f = tid + i * 256;            // 0..1023 half8 chunks
        int r = f >> 4, c8 = f & 15;
        float4 raw = *(const float4*)(in + (size_t)(rb + r) * CH + c8 * 8);
        if (RELU) {
            __half2* h2 = (__half2*)&raw;
#pragma unroll
            for (int u = 0; u < 4; ++u) {
                float2 fv = __half22float2(h2[u]);
                h2[u] = __floats2half2_rn(fmaxf(fv.x, 0.f), fmaxf(fv.y, 0.f));
            }
        }
        *(float4*)&xs[r][c8 * 8] = raw;
    }
    stage_w(wt, Wt, tid);
    __syncthreads();
    mfma_body<BIAS, ATTN>(xs, wt, bias, att, out8, s, rb, tid);
}

// ------- per-src-node softmax denom (no max-sub; |t|<~20 safe in fp32) -----
__global__ __launch_bounds__(256)
void softmax_stats(const int* __restrict__ cur_s,
                   const unsigned short* __restrict__ pad_dst,
                   const float* __restrict__ s, float* __restrict__ ssum)
{
    int node = (blockIdx.x * 256 + threadIdx.x) >> 6;
    int lane = threadIdx.x & 63;
    if (node >= NN) return;
    int deg = min(cur_s[node], CAP);
    float si = s[node];
    float sum = 0.f;
    if (lane < deg) {
        int d = pad_dst[node * CAP + lane];
        float t = si + s[d];
        t = t > 0.f ? t : 0.2f * t;
        sum = expf(t);
    }
#pragma unroll
    for (int o = 32; o; o >>= 1) sum += __shfl_xor(sum, o);
    if (lane == 0) ssum[node] = sum;
}

// ------- gather core: quad-edge scheme (one node per wave, max TLP) --------
// 4 quarters of 16 lanes; quarter q handles edges base+4u+q. Each lane reads
// uint2 = 8 fp8 (channels 8cl..8cl+7); combine via shfl_xor(16)+shfl_xor(32).
// Lanes >= deg: src=0,w=0 -> weight-0 row-0 reads.
// OM=0: fp16 row out. OM=1: relu + fp8 row out (feeds the layer-3 gather).
template<int OM>
__device__ __forceinline__
void gather_core(int node, int lane, int deg, int src, float w,
                 const unsigned char* __restrict__ h8p, void* __restrict__ outrow)
{
    int qtr = lane >> 4, cl = lane & 15;
    float a[8] = {};
    for (int base = 0; base < deg; base += 8) {
        uint2 v[2]; float wj[2];
#pragma unroll
        for (int u = 0; u < 2; ++u) {
            int e = base + 4 * u + qtr;           // e <= deg+7 <= 55 < 64
            int sj = __shfl(src, e);
            wj[u]  = __shfl(w, e);
            v[u] = ((const uint2*)(h8p + (size_t)sj * CH))[cl];
        }
#pragma unroll
        for (int u = 0; u < 2; ++u)
            decode_fma8(v[u], wj[u], a);
    }
#pragma unroll
    for (int k = 0; k < 8; ++k) {
        a[k] += __shfl_xor(a[k], 16);
        a[k] += __shfl_xor(a[k], 32);
    }
    if (qtr == 0) {
        if (OM == 0) {
            float4 st;
            ((__half2*)&st)[0] = __floats2half2_rn(a[0], a[1]);
            ((__half2*)&st)[1] = __floats2half2_rn(a[2], a[3]);
            ((__half2*)&st)[2] = __floats2half2_rn(a[4], a[5]);
            ((__half2*)&st)[3] = __floats2half2_rn(a[6], a[7]);
            ((float4*)outrow)[cl] = st;
        } else {
            unsigned lo = pack_fp8x4_relu(a[0], a[1], a[2], a[3]);
            unsigned hi = pack_fp8x4_relu(a[4], a[5], a[6], a[7]);
            ((uint2*)outrow)[cl] = make_uint2(lo, hi);
        }
    }
}

// ------- GT aggregation ----------------------------------------------------
// F8OUT=false (layer 1): fp16 out for gemm_k2. F8OUT=true (layer 2): relu'd
// fp8 out, consumed directly by gcn_gather (layer-3 gemm eliminated).
template<bool F8OUT>
__global__ __launch_bounds__(256)
void gt_gather(const int* __restrict__ cur_d,
               const unsigned short* __restrict__ pad_src,
               const unsigned char* __restrict__ h8p, const float* __restrict__ s,
               const float* __restrict__ ssum, __half* __restrict__ out16,
               unsigned char* __restrict__ o8)
{
    int node = (blockIdx.x * 256 + threadIdx.x) >> 6;
    int lane = threadIdx.x & 63;
    if (node >= NN) return;
    int deg = min(cur_d[node], CAP);
    float sd = s[node];
    int src = 0; float w = 0.f;
    if (lane < deg) {
        src = pad_src[node * CAP + lane];
        float t = sd + s[src];
        t = t > 0.f ? t : 0.2f * t;
        w = expf(t) / ssum[src];
    }
    if (F8OUT)
        gather_core<1>(node, lane, deg, src, w, h8p, o8 + (size_t)node * CH);
    else
        gather_core<0>(node, lane, deg, src, w, h8p, out16 + (size_t)node * CH);
}

// ------- GCN aggregation, inline dinv; split fp16 output (buffer reuse) ----
__global__ __launch_bounds__(256)
void gcn_gather(const int* __restrict__ cur_d,
                const unsigned short* __restrict__ pad_src,
                const unsigned char* __restrict__ h8p,
                __half* __restrict__ outA, __half* __restrict__ outB)
{
    int node = (blockIdx.x * 256 + threadIdx.x) >> 6;
    int lane = threadIdx.x & 63;
    if (node >= NN) return;
    int dn = cur_d[node];
    int deg = min(dn, CAP);
    float nu = rsqrtf((float)max(dn, 1));
    int src = 0; float w = 0.f;
    if (lane < deg) {
        src = pad_src[node * CAP + lane];
        w = rsqrtf((float)max(cur_d[src], 1)) * nu;
    }
    __half* row = (node < NSPLIT) ? outA + (size_t)node * CH
                                  : outB + (size_t)(node - NSPLIT) * CH;
    gather_core<0>(node, lane, deg, src, w, h8p, row);
}

// ---- pooling: 8-deep batched loads; boundary branch is block-uniform ------
// Input rows split: [0,20000) in hA, [20000,40000) in hB; 500 blocks x 80
// rows -> block 250 starts exactly at the split (no straddle).
__global__ __launch_bounds__(128)
void pool_part(const __half* __restrict__ hA, const __half* __restrict__ hB,
               const int* __restrict__ batch, float* __restrict__ pooled)
{
    int ch = threadIdx.x;
    int start = blockIdx.x * 80;
    const __half* hp = (start < NSPLIT) ? hA + (size_t)start * CH
                                        : hB + (size_t)(start - NSPLIT) * CH;
    float acc = 0.f;
    int curg = batch[start];
    for (int base = start; base < start + 80; base += 8) {
        float vals[8]; int gs[8];
#pragma unroll
        for (int u = 0; u < 8; ++u)
            vals[u] = __half2float(hp[(size_t)(base - start + u) * CH + ch]);
#pragma unroll
        for (int u = 0; u < 8; ++u) gs[u] = batch[base + u];
#pragma unroll
        for (int u = 0; u < 8; ++u) {
            if (gs[u] != curg) {
                atomicAdd(pooled + (size_t)curg * CH + ch, acc);
                acc = 0.f; curg = gs[u];
            }
            acc += vals[u];
        }
    }
    atomicAdd(pooled + (size_t)curg * CH + ch, acc);
}

// ---- head: logits = (psum/cnt) @ Wgf + bgf; log_softmax -------------------
__global__ __launch_bounds__(256)
void head_kernel(const float* __restrict__ psum, const int* __restrict__ gstart,
                 const float* __restrict__ Wgf, const float* __restrict__ bgf,
                 float* __restrict__ out)
{
    __shared__ float lg[NG][OC];
    int tid = threadIdx.x;
#pragma unroll
    for (int i = 0; i < 4; ++i) {
        int f = tid + i * 256;        // 0..1023
        int g = f >> 4, o = f & 15;
        float cnt = fmaxf((float)(gstart[g + 1] - gstart[g]), 1.0f);
        float inv = 1.0f / cnt;
        float acc = bgf[o];
        for (int c = 0; c < CH; ++c)
            acc += psum[g * CH + c] * inv * Wgf[c * OC + o];
        lg[g][o] = acc;
    }
    __syncthreads();
    if (tid < NG) {
        float m = -1e30f;
#pragma unroll
        for (int o = 0; o < OC; ++o) m = fmaxf(m, lg[tid][o]);
        float sum = 0.f;
#pragma unroll
        for (int o = 0; o < OC; ++o) sum += expf(lg[tid][o] - m);
        float lse = m + logf(sum);
#pragma unroll
        for (int o = 0; o < OC; ++o) out[tid * OC + o] = lg[tid][o] - lse;
    }
}

extern "C" void kernel_launch(void* const* d_in, const int* in_sizes, int n_in,
                              void* d_out, int out_size, void* d_ws, size_t ws_size,
                              hipStream_t stream)
{
    const float* x     = (const float*)d_in[0];
    const int*   ei    = (const int*)d_in[1];
    const int*   batch = (const int*)d_in[2];
    const float* W1    = (const float*)d_in[3];
    const float* b1    = (const float*)d_in[4];
    const float* att1  = (const float*)d_in[5];
    const float* W2    = (const float*)d_in[6];
    const float* b2    = (const float*)d_in[7];
    const float* att2  = (const float*)d_in[8];
    const float* Wg    = (const float*)d_in[9];
    const float* bg    = (const float*)d_in[10];
    const float* Wfc   = (const float*)d_in[11];
    const float* bfc   = (const float*)d_in[12];
    float* out = (float*)d_out;

    const size_t NNCH = (size_t)NN * CH;
    __half* B16 = (__half*)d_ws;                       // [NN*CH] fp16 scratch
    unsigned char* A8 = (unsigned char*)(B16 + NNCH);  // [NN*CH] fp8 scratch
    // Layer-3 buffer reuse (x2 and h2 are dead at the point of each reuse):
    unsigned char* G8 = (unsigned char*)B16;           // relu(x3) fp8, 5.12 MB
    __half* GO_A = B16 + (size_t)NSPLIT * CH;          // gcn out rows 0..19999
    __half* GO_B = (__half*)A8;                        // gcn out rows 20000..39999
    _Float16* Wt1 = (_Float16*)(A8 + NNCH);            // [CH*CH]
    _Float16* Wt2 = Wt1 + CH * CH;
    float* Wgf    = (float*)(Wt2 + CH * CH);           // [CH*OC]
    float* bgf    = Wgf + CH * OC;                     // [OC]
    int*   cur_d  = (int*)(bgf + OC);                  // [NN]
    int*   cur_s  = cur_d + NN;                        // [NN]
    float* s1     = (float*)(cur_s + NN);              // [NN]
    float* s2     = s1 + NN;                           // [NN]
    float* ssum   = s2 + NN;                           // [NN]
    float* pooled = ssum + NN;                         // [NG*CH]
    int*   gstart = (int*)(pooled + NG * CH);          // [NG+1]
    unsigned short* pad_src = (unsigned short*)(gstart + NG + 1);  // [NN*CAP]
    unsigned short* pad_dst = pad_src + (size_t)NN * CAP;          // [NN*CAP]

    const int WB = NN / 4;                 // 10000 (wave-per-node grids)

    prep<<<157, 256, 0, stream>>>(batch, gstart, cur_d, cur_s, pooled,
                                  W1, W2, Wg, Wfc, bg, bfc, Wt1, Wt2, Wgf, bgf);

    // ---- GT layer 1: gemm1 co-resident with CSR fill ----------------------
    fill_gemm1<<<NBLK1, 256, 0, stream>>>(
        x, Wt1, b1, att1, A8, s1, ei, cur_d, cur_s, pad_src, pad_dst);
    softmax_stats<<<WB, 256, 0, stream>>>(cur_s, pad_dst, s1, ssum);
    gt_gather<false><<<WB, 256, 0, stream>>>(cur_d, pad_src, A8, s1, ssum,
                                             B16, nullptr);

    // ---- GT layer 2 (relu folded into gemm input read) --------------------
    gemm_k<true, true, true><<<NGEMMB, 256, 0, stream>>>(
        B16, Wt2, b2, att2, A8, s2);
    softmax_stats<<<WB, 256, 0, stream>>>(cur_s, pad_dst, s2, ssum);
    gt_gather<true><<<WB, 256, 0, stream>>>(cur_d, pad_src, A8, s2, ssum,
                                            nullptr, G8);

    // ---- GCN layer: gather only (Wg folded into head via Wgf) -------------
    gcn_gather<<<WB, 256, 0, stream>>>(cur_d, pad_src, G8, GO_A, GO_B);

    // ---- pool + head ------------------------------------------------------
    pool_part<<<500, 128, 0, stream>>>(GO_A, GO_B, batch, pooled);
    head_kernel<<<1, 256, 0, stream>>>(pooled, gstart, Wgf, bgf, out);
}

// Round 10
// 259.933 us; speedup vs baseline: 1.0248x; 1.0024x over previous
//
#include <hip/hip_runtime.h>
#include <hip/hip_fp16.h>
#include <hip/hip_fp8.h>
#include <math.h>

#define NN 40000      // nodes
#define NE 640000     // raw edges
#define ET 680000     // edges + self loops
#define CH 128
#define OC 16
#define NG 64
#define NQ (ET/4)     // 170000 edge quads
#define CAP 48        // padded-CSR capacity per node (deg ~ Poisson(17))
#define NFILLB 665    // one block per 256 quads (unbucketed single pass)
#define NGEMMB 625    // 64-row tiles (full 128 cols internal)
#define NBLK1 (2*NGEMMB + (NFILLB - NGEMMB))   // 1290: pairwise interleave + tail
#define NSPLIT 20000  // gcn-out row split (pool block boundary: 20000/80=250)

typedef _Float16 h8 __attribute__((ext_vector_type(8)));
typedef float    f4 __attribute__((ext_vector_type(4)));
typedef float    f2 __attribute__((ext_vector_type(2)));

// ---- fp8 e4m3 conversions: HARDWARE path (v_cvt_pk_*_fp8, OCP on gfx950) --
#if __has_builtin(__builtin_amdgcn_cvt_pk_f32_fp8) && __has_builtin(__builtin_amdgcn_cvt_pk_fp8_f32)
#define FP8_HW 1
#else
#define FP8_HW 0
#endif

__device__ __forceinline__ float2 fp8x2_to_f32_sw(unsigned short v) {
    __hip_fp8_e4m3 a, b;
    a.__x = (__hip_fp8_storage_t)(v & 0xff);
    b.__x = (__hip_fp8_storage_t)(v >> 8);
    return make_float2((float)a, (float)b);
}

__device__ __forceinline__ unsigned char f32_to_fp8(float f) {
#if FP8_HW
    return (unsigned char)(__builtin_amdgcn_cvt_pk_fp8_f32(f, f, 0, false) & 0xff);
#else
    __hip_fp8_e4m3 t(f);
    return (unsigned char)t.__x;
#endif
}

// decode 8 fp8 bytes (uint2) and accumulate a[k] += val[k]*w
__device__ __forceinline__ void decode_fma8(uint2 v, float w, float* a) {
#if FP8_HW
    f2 p0 = __builtin_amdgcn_cvt_pk_f32_fp8((int)v.x, false);
    f2 p1 = __builtin_amdgcn_cvt_pk_f32_fp8((int)v.x, true);
    f2 p2 = __builtin_amdgcn_cvt_pk_f32_fp8((int)v.y, false);
    f2 p3 = __builtin_amdgcn_cvt_pk_f32_fp8((int)v.y, true);
    a[0] += p0[0] * w; a[1] += p0[1] * w;
    a[2] += p1[0] * w; a[3] += p1[1] * w;
    a[4] += p2[0] * w; a[5] += p2[1] * w;
    a[6] += p3[0] * w; a[7] += p3[1] * w;
#else
    float2 p0 = fp8x2_to_f32_sw((unsigned short)(v.x & 0xffff));
    float2 p1 = fp8x2_to_f32_sw((unsigned short)(v.x >> 16));
    float2 p2 = fp8x2_to_f32_sw((unsigned short)(v.y & 0xffff));
    float2 p3 = fp8x2_to_f32_sw((unsigned short)(v.y >> 16));
    a[0] += p0.x * w; a[1] += p0.y * w;
    a[2] += p1.x * w; a[3] += p1.y * w;
    a[4] += p2.x * w; a[5] += p2.y * w;
    a[6] += p3.x * w; a[7] += p3.y * w;
#endif
}

// pack 4 f32 (relu'd) into 4 fp8 bytes of a uint
__device__ __forceinline__ unsigned pack_fp8x4_relu(float a0, float a1,
                                                    float a2, float a3) {
#if FP8_HW
    int w = __builtin_amdgcn_cvt_pk_fp8_f32(fmaxf(a0, 0.f), fmaxf(a1, 0.f), 0, false);
    w = __builtin_amdgcn_cvt_pk_fp8_f32(fmaxf(a2, 0.f), fmaxf(a3, 0.f), w, true);
    return (unsigned)w;
#else
    return (unsigned)f32_to_fp8(fmaxf(a0, 0.f))
         | ((unsigned)f32_to_fp8(fmaxf(a1, 0.f)) << 8)
         | ((unsigned)f32_to_fp8(fmaxf(a2, 0.f)) << 16)
         | ((unsigned)f32_to_fp8(fmaxf(a3, 0.f)) << 24);
#endif
}

// ---- prep: zero scratch + graph bounds + W->fp16 transposed + Wg folding --
// Layer-3 algebra: gather/pool/Wg commute (all linear), so Wg is folded into
// the head: Wgf = Wg@Wfc [128x16], bgf = bg@Wfc + bfc [16]. gemm_k3 deleted.
__global__ __launch_bounds__(256)
void prep(const int* __restrict__ batch, int* __restrict__ gstart,
          int* __restrict__ cur_d, int* __restrict__ cur_s,
          float* __restrict__ pooled,
          const float* __restrict__ W1, const float* __restrict__ W2,
          const float* __restrict__ Wg, const float* __restrict__ Wfc,
          const float* __restrict__ bg, const float* __restrict__ bfc,
          _Float16* __restrict__ Wt1, _Float16* __restrict__ Wt2,
          float* __restrict__ Wgf, float* __restrict__ bgf)
{
    int i = blockIdx.x * 256 + threadIdx.x;
    if (i < NN) {
        cur_d[i] = 0; cur_s[i] = 0;
        int b = batch[i];
        if (i == 0) { for (int g = 0; g <= b; ++g) gstart[g] = 0; }
        else { int pb = batch[i - 1]; for (int g = pb + 1; g <= b; ++g) gstart[g] = i; }
        if (i == NN - 1) { for (int g = b + 1; g <= NG; ++g) gstart[g] = NN; }
    }
    if (i < NG * CH) pooled[i] = 0.f;
    if (i < CH * CH) {
        int k = i >> 7, n = i & 127;          // coalesced read W[k][n]
        Wt1[n * CH + k] = (_Float16)W1[i];
        Wt2[n * CH + k] = (_Float16)W2[i];
    }
    if (i < CH * OC) {                        // Wgf[k][o] = sum_c Wg[k][c]*Wfc[c][o]
        int k = i >> 4, o = i & 15;
        float acc = 0.f;
        for (int c = 0; c < CH; ++c)
            acc += Wg[k * CH + c] * Wfc[c * OC + o];
        Wgf[k * OC + o] = acc;
    }
    if (i >= CH * OC && i < CH * OC + OC) {   // bgf[o] = sum_c bg[c]*Wfc[c][o] + bfc[o]
        int o = i - CH * OC;
        float acc = bfc[o];
        for (int c = 0; c < CH; ++c)
            acc += bg[c] * Wfc[c * OC + o];
        bgf[o] = acc;
    }
}

// ---- stage Wt (global, [n][k] row-major) into LDS wt[128][136] ------------
__device__ __forceinline__
void stage_w(_Float16 (*wt)[136], const _Float16* __restrict__ Wt, int tid)
{
#pragma unroll
    for (int i = 0; i < 8; ++i) {
        int f = tid + i * 256;            // 0..2047 half8 chunks
        int n = f >> 4, c8 = f & 15;
        *(float4*)&wt[n][c8 * 8] = *(const float4*)(Wt + (size_t)n * CH + c8 * 8);
    }
}

// ---- MFMA body: 64 rows x 128 cols, K=128; xs and wt staged in LDS --------
// A-frag A[m][k=quad*8+j]; C/D col=lane&15, row=quad*4+reg (verified R6).
// b128 LDS reads process 16 lanes/phase -> (m,quad) mapping is 2-way/phase,
// conflict-free. Full row per block -> s[row] is a plain store (no atomic).
template<bool BIAS, bool ATTN>
__device__ __forceinline__
void mfma_body(_Float16 (*xs)[136], _Float16 (*wt)[136],
               const float* __restrict__ bias, const float* __restrict__ att,
               unsigned char* __restrict__ out8, float* __restrict__ s,
               int rb, int tid)
{
    const int wv = tid >> 6, lane = tid & 63;
    const int m = lane & 15, quad = lane >> 4;
    f4 acc[8] = {};
#pragma unroll
    for (int ks = 0; ks < 4; ++ks) {
        h8 a = *(const h8*)&xs[wv * 16 + m][ks * 32 + quad * 8];
#pragma unroll
        for (int t = 0; t < 8; ++t) {
            h8 b = *(const h8*)&wt[t * 16 + m][ks * 32 + quad * 8];
            acc[t] = __builtin_amdgcn_mfma_f32_16x16x32_f16(a, b, acc[t], 0, 0, 0);
        }
    }
    float pr[4] = {0.f, 0.f, 0.f, 0.f};
#pragma unroll
    for (int t = 0; t < 8; ++t) {
        int col = t * 16 + m;
        float bv = BIAS ? bias[col] : 0.f;
        float av = ATTN ? att[col] : 0.f;
#pragma unroll
        for (int r = 0; r < 4; ++r) {
            float o = acc[t][r] + bv;
            int row = rb + wv * 16 + quad * 4 + r;
            out8[(size_t)row * CH + col] = f32_to_fp8(o);
            if (ATTN) pr[r] += o * av;
        }
    }
    if (ATTN) {
#pragma unroll
        for (int r = 0; r < 4; ++r) {
            float p = pr[r];
            p += __shfl_xor(p, 1); p += __shfl_xor(p, 2);
            p += __shfl_xor(p, 4); p += __shfl_xor(p, 8);
            if (m == 0) s[rb + wv * 16 + quad * 4 + r] = p;  // full row here
        }
    }
}

// ---- fill body: unbucketed padded-CSR fill, 4 edges/thread, both sides ----
// ATOMIC BURST: all 8 returning atomics are independent (distinct chains), so
// issue them ALL before any dependent scatter store. The old interleaved form
// serialized 8x ~600cy atomic->store chains per thread; at 3 blocks/CU (LDS
// charged to fill blocks too) there is too little TLP to hide that. Burst
// form pays the atomic latency ~once instead of 8x if latency-bound.
__device__ __forceinline__
void fill_body(int fb, int tid, const int* __restrict__ ei,
               int* __restrict__ cur_d, int* __restrict__ cur_s,
               unsigned short* __restrict__ pad_src,
               unsigned short* __restrict__ pad_dst)
{
    int q = fb * 256 + tid;
    if (q >= NQ) return;
    int e0 = q * 4;
    int4 sv, dv;
    if (e0 < NE) {                          // quads never straddle NE (NE%4==0)
        sv = *(const int4*)(ei + e0);
        dv = *(const int4*)(ei + NE + e0);
    } else {
        int b = e0 - NE;
        sv = make_int4(b, b + 1, b + 2, b + 3);
        dv = sv;
    }
    const int* sc = (const int*)&sv;
    const int* dc = (const int*)&dv;
    int pd[4], ps[4];
#pragma unroll
    for (int u = 0; u < 4; ++u) pd[u] = atomicAdd(cur_d + dc[u], 1);
#pragma unroll
    for (int u = 0; u < 4; ++u) ps[u] = atomicAdd(cur_s + sc[u], 1);
#pragma unroll
    for (int u = 0; u < 4; ++u)
        if (pd[u] < CAP) pad_src[dc[u] * CAP + pd[u]] = (unsigned short)sc[u];
#pragma unroll
    for (int u = 0; u < 4; ++u)
        if (ps[u] < CAP) pad_dst[sc[u] * CAP + ps[u]] = (unsigned short)dc[u];
}

// ---- fused gemm1 + fill, pairwise-interleaved for co-residency ------------
__global__ __launch_bounds__(256)
void fill_gemm1(const float* __restrict__ x, const _Float16* __restrict__ Wt1,
                const float* __restrict__ b1, const float* __restrict__ att1,
                unsigned char* __restrict__ out8, float* __restrict__ s1,
                const int* __restrict__ ei, int* __restrict__ cur_d,
                int* __restrict__ cur_s, unsigned short* __restrict__ pad_src,
                unsigned short* __restrict__ pad_dst)
{
    __shared__ __attribute__((aligned(16))) _Float16 xs[64][136];
    __shared__ __attribute__((aligned(16))) _Float16 wt[128][136];
    int bid = blockIdx.x;
    if (bid < 2 * NGEMMB && (bid & 1) == 0) {
        int g = bid >> 1;
        int rb = g * 64, tid = threadIdx.x;
#pragma unroll
        for (int i = 0; i < 4; ++i) {
            int f = tid + i * 256;
            int r = f >> 4, c8 = f & 15;
            const float* p = x + (size_t)(rb + r) * CH + c8 * 8;
            float4 v0 = *(const float4*)p;
            float4 v1 = *(const float4*)(p + 4);
            __half2 h[4] = { __floats2half2_rn(v0.x, v0.y), __floats2half2_rn(v0.z, v0.w),
                             __floats2half2_rn(v1.x, v1.y), __floats2half2_rn(v1.z, v1.w) };
            *(float4*)&xs[r][c8 * 8] = *(float4*)h;
        }
        stage_w(wt, Wt1, tid);
        __syncthreads();
        mfma_body<true, true>(xs, wt, b1, att1, out8, s1, rb, tid);
        return;
    }
    int fb = (bid < 2 * NGEMMB) ? (bid >> 1) : (NGEMMB + (bid - 2 * NGEMMB));
    if (fb < NFILLB)
        fill_body(fb, threadIdx.x, ei, cur_d, cur_s, pad_src, pad_dst);
}

// ---- standalone gemm (layer 2): stage fp16 input + W, run MFMA ------------
template<bool RELU, bool BIAS, bool ATTN>
__global__ __launch_bounds__(256)
void gemm_k(const __half* __restrict__ in, const _Float16* __restrict__ Wt,
            const float* __restrict__ bias, const float* __restrict__ att,
            unsigned char* __restrict__ out8, float* __restrict__ s)
{
    __shared__ __attribute__((aligned(16))) _Float16 xs[64][136];
    __shared__ __attribute__((aligned(16))) _Float16 wt[128][136];
    const int tid = threadIdx.x;
    const int rb = blockIdx.x * 64;
#pragma unroll
    for (int i = 0; i < 4; ++i) {
        int f = tid + i * 256;            // 0..1023 half8 chunks
        int r = f >> 4, c8 = f & 15;
        float4 raw = *(const float4*)(in + (size_t)(rb + r) * CH + c8 * 8);
        if (RELU) {
            __half2* h2 = (__half2*)&raw;
#pragma unroll
            for (int u = 0; u < 4; ++u) {
                float2 fv = __half22float2(h2[u]);
                h2[u] = __floats2half2_rn(fmaxf(fv.x, 0.f), fmaxf(fv.y, 0.f));
            }
        }
        *(float4*)&xs[r][c8 * 8] = raw;
    }
    stage_w(wt, Wt, tid);
    __syncthreads();
    mfma_body<BIAS, ATTN>(xs, wt, bias, att, out8, s, rb, tid);
}

// ------- per-src-node softmax denom (no max-sub; |t|<~20 safe in fp32) -----
__global__ __launch_bounds__(256)
void softmax_stats(const int* __restrict__ cur_s,
                   const unsigned short* __restrict__ pad_dst,
                   const float* __restrict__ s, float* __restrict__ ssum)
{
    int node = (blockIdx.x * 256 + threadIdx.x) >> 6;
    int lane = threadIdx.x & 63;
    if (node >= NN) return;
    int deg = min(cur_s[node], CAP);
    float si = s[node];
    float sum = 0.f;
    if (lane < deg) {
        int d = pad_dst[node * CAP + lane];
        float t = si + s[d];
        t = t > 0.f ? t : 0.2f * t;
        sum = expf(t);
    }
#pragma unroll
    for (int o = 32; o; o >>= 1) sum += __shfl_xor(sum, o);
    if (lane == 0) ssum[node] = sum;
}

// ------- gather core: quad-edge scheme (one node per wave, max TLP) --------
// 4 quarters of 16 lanes; quarter q handles edges base+4u+q. Each lane reads
// uint2 = 8 fp8 (channels 8cl..8cl+7); combine via shfl_xor(16)+shfl_xor(32).
// Lanes >= deg: src=0,w=0 -> weight-0 row-0 reads.
// OM=0: fp16 row out. OM=1: relu + fp8 row out (feeds the layer-3 gather).
template<int OM>
__device__ __forceinline__
void gather_core(int node, int lane, int deg, int src, float w,
                 const unsigned char* __restrict__ h8p, void* __restrict__ outrow)
{
    int qtr = lane >> 4, cl = lane & 15;
    float a[8] = {};
    for (int base = 0; base < deg; base += 8) {
        uint2 v[2]; float wj[2];
#pragma unroll
        for (int u = 0; u < 2; ++u) {
            int e = base + 4 * u + qtr;           // e <= deg+7 <= 55 < 64
            int sj = __shfl(src, e);
            wj[u]  = __shfl(w, e);
            v[u] = ((const uint2*)(h8p + (size_t)sj * CH))[cl];
        }
#pragma unroll
        for (int u = 0; u < 2; ++u)
            decode_fma8(v[u], wj[u], a);
    }
#pragma unroll
    for (int k = 0; k < 8; ++k) {
        a[k] += __shfl_xor(a[k], 16);
        a[k] += __shfl_xor(a[k], 32);
    }
    if (qtr == 0) {
        if (OM == 0) {
            float4 st;
            ((__half2*)&st)[0] = __floats2half2_rn(a[0], a[1]);
            ((__half2*)&st)[1] = __floats2half2_rn(a[2], a[3]);
            ((__half2*)&st)[2] = __floats2half2_rn(a[4], a[5]);
            ((__half2*)&st)[3] = __floats2half2_rn(a[6], a[7]);
            ((float4*)outrow)[cl] = st;
        } else {
            unsigned lo = pack_fp8x4_relu(a[0], a[1], a[2], a[3]);
            unsigned hi = pack_fp8x4_relu(a[4], a[5], a[6], a[7]);
            ((uint2*)outrow)[cl] = make_uint2(lo, hi);
        }
    }
}

// ------- GT aggregation ----------------------------------------------------
// F8OUT=false (layer 1): fp16 out for gemm_k2. F8OUT=true (layer 2): relu'd
// fp8 out, consumed directly by gcn_gather (layer-3 gemm eliminated).
template<bool F8OUT>
__global__ __launch_bounds__(256)
void gt_gather(const int* __restrict__ cur_d,
               const unsigned short* __restrict__ pad_src,
               const unsigned char* __restrict__ h8p, const float* __restrict__ s,
               const float* __restrict__ ssum, __half* __restrict__ out16,
               unsigned char* __restrict__ o8)
{
    int node = (blockIdx.x * 256 + threadIdx.x) >> 6;
    int lane = threadIdx.x & 63;
    if (node >= NN) return;
    int deg = min(cur_d[node], CAP);
    float sd = s[node];
    int src = 0; float w = 0.f;
    if (lane < deg) {
        src = pad_src[node * CAP + lane];
        float t = sd + s[src];
        t = t > 0.f ? t : 0.2f * t;
        w = expf(t) / ssum[src];
    }
    if (F8OUT)
        gather_core<1>(node, lane, deg, src, w, h8p, o8 + (size_t)node * CH);
    else
        gather_core<0>(node, lane, deg, src, w, h8p, out16 + (size_t)node * CH);
}

// ------- GCN aggregation, inline dinv; split fp16 output (buffer reuse) ----
__global__ __launch_bounds__(256)
void gcn_gather(const int* __restrict__ cur_d,
                const unsigned short* __restrict__ pad_src,
                const unsigned char* __restrict__ h8p,
                __half* __restrict__ outA, __half* __restrict__ outB)
{
    int node = (blockIdx.x * 256 + threadIdx.x) >> 6;
    int lane = threadIdx.x & 63;
    if (node >= NN) return;
    int dn = cur_d[node];
    int deg = min(dn, CAP);
    float nu = rsqrtf((float)max(dn, 1));
    int src = 0; float w = 0.f;
    if (lane < deg) {
        src = pad_src[node * CAP + lane];
        w = rsqrtf((float)max(cur_d[src], 1)) * nu;
    }
    __half* row = (node < NSPLIT) ? outA + (size_t)node * CH
                                  : outB + (size_t)(node - NSPLIT) * CH;
    gather_core<0>(node, lane, deg, src, w, h8p, row);
}

// ---- pooling: 8-deep batched loads; boundary branch is block-uniform ------
// Input rows split: [0,20000) in hA, [20000,40000) in hB; 500 blocks x 80
// rows -> block 250 starts exactly at the split (no straddle).
__global__ __launch_bounds__(128)
void pool_part(const __half* __restrict__ hA, const __half* __restrict__ hB,
               const int* __restrict__ batch, float* __restrict__ pooled)
{
    int ch = threadIdx.x;
    int start = blockIdx.x * 80;
    const __half* hp = (start < NSPLIT) ? hA + (size_t)start * CH
                                        : hB + (size_t)(start - NSPLIT) * CH;
    float acc = 0.f;
    int curg = batch[start];
    for (int base = start; base < start + 80; base += 8) {
        float vals[8]; int gs[8];
#pragma unroll
        for (int u = 0; u < 8; ++u)
            vals[u] = __half2float(hp[(size_t)(base - start + u) * CH + ch]);
#pragma unroll
        for (int u = 0; u < 8; ++u) gs[u] = batch[base + u];
#pragma unroll
        for (int u = 0; u < 8; ++u) {
            if (gs[u] != curg) {
                atomicAdd(pooled + (size_t)curg * CH + ch, acc);
                acc = 0.f; curg = gs[u];
            }
            acc += vals[u];
        }
    }
    atomicAdd(pooled + (size_t)curg * CH + ch, acc);
}

// ---- head: logits = (psum/cnt) @ Wgf + bgf; log_softmax -------------------
__global__ __launch_bounds__(256)
void head_kernel(const float* __restrict__ psum, const int* __restrict__ gstart,
                 const float* __restrict__ Wgf, const float* __restrict__ bgf,
                 float* __restrict__ out)
{
    __shared__ float lg[NG][OC];
    int tid = threadIdx.x;
#pragma unroll
    for (int i = 0; i < 4; ++i) {
        int f = tid + i * 256;        // 0..1023
        int g = f >> 4, o = f & 15;
        float cnt = fmaxf((float)(gstart[g + 1] - gstart[g]), 1.0f);
        float inv = 1.0f / cnt;
        float acc = bgf[o];
        for (int c = 0; c < CH; ++c)
            acc += psum[g * CH + c] * inv * Wgf[c * OC + o];
        lg[g][o] = acc;
    }
    __syncthreads();
    if (tid < NG) {
        float m = -1e30f;
#pragma unroll
        for (int o = 0; o < OC; ++o) m = fmaxf(m, lg[tid][o]);
        float sum = 0.f;
#pragma unroll
        for (int o = 0; o < OC; ++o) sum += expf(lg[tid][o] - m);
        float lse = m + logf(sum);
#pragma unroll
        for (int o = 0; o < OC; ++o) out[tid * OC + o] = lg[tid][o] - lse;
    }
}

extern "C" void kernel_launch(void* const* d_in, const int* in_sizes, int n_in,
                              void* d_out, int out_size, void* d_ws, size_t ws_size,
                              hipStream_t stream)
{
    const float* x     = (const float*)d_in[0];
    const int*   ei    = (const int*)d_in[1];
    const int*   batch = (const int*)d_in[2];
    const float* W1    = (const float*)d_in[3];
    const float* b1    = (const float*)d_in[4];
    const float* att1  = (const float*)d_in[5];
    const float* W2    = (const float*)d_in[6];
    const float* b2    = (const float*)d_in[7];
    const float* att2  = (const float*)d_in[8];
    const float* Wg    = (const float*)d_in[9];
    const float* bg    = (const float*)d_in[10];
    const float* Wfc   = (const float*)d_in[11];
    const float* bfc   = (const float*)d_in[12];
    float* out = (float*)d_out;

    const size_t NNCH = (size_t)NN * CH;
    __half* B16 = (__half*)d_ws;                       // [NN*CH] fp16 scratch
    unsigned char* A8 = (unsigned char*)(B16 + NNCH);  // [NN*CH] fp8 scratch
    // Layer-3 buffer reuse (x2 and h2 are dead at the point of each reuse):
    unsigned char* G8 = (unsigned char*)B16;           // relu(x3) fp8, 5.12 MB
    __half* GO_A = B16 + (size_t)NSPLIT * CH;          // gcn out rows 0..19999
    __half* GO_B = (__half*)A8;                        // gcn out rows 20000..39999
    _Float16* Wt1 = (_Float16*)(A8 + NNCH);            // [CH*CH]
    _Float16* Wt2 = Wt1 + CH * CH;
    float* Wgf    = (float*)(Wt2 + CH * CH);           // [CH*OC]
    float* bgf    = Wgf + CH * OC;                     // [OC]
    int*   cur_d  = (int*)(bgf + OC);                  // [NN]
    int*   cur_s  = cur_d + NN;                        // [NN]
    float* s1     = (float*)(cur_s + NN);              // [NN]
    float* s2     = s1 + NN;                           // [NN]
    float* ssum   = s2 + NN;                           // [NN]
    float* pooled = ssum + NN;                         // [NG*CH]
    int*   gstart = (int*)(pooled + NG * CH);          // [NG+1]
    unsigned short* pad_src = (unsigned short*)(gstart + NG + 1);  // [NN*CAP]
    unsigned short* pad_dst = pad_src + (size_t)NN * CAP;          // [NN*CAP]

    const int WB = NN / 4;                 // 10000 (wave-per-node grids)

    prep<<<157, 256, 0, stream>>>(batch, gstart, cur_d, cur_s, pooled,
                                  W1, W2, Wg, Wfc, bg, bfc, Wt1, Wt2, Wgf, bgf);

    // ---- GT layer 1: gemm1 co-resident with CSR fill ----------------------
    fill_gemm1<<<NBLK1, 256, 0, stream>>>(
        x, Wt1, b1, att1, A8, s1, ei, cur_d, cur_s, pad_src, pad_dst);
    softmax_stats<<<WB, 256, 0, stream>>>(cur_s, pad_dst, s1, ssum);
    gt_gather<false><<<WB, 256, 0, stream>>>(cur_d, pad_src, A8, s1, ssum,
                                             B16, nullptr);

    // ---- GT layer 2 (relu folded into gemm input read) --------------------
    gemm_k<true, true, true><<<NGEMMB, 256, 0, stream>>>(
        B16, Wt2, b2, att2, A8, s2);
    softmax_stats<<<WB, 256, 0, stream>>>(cur_s, pad_dst, s2, ssum);
    gt_gather<true><<<WB, 256, 0, stream>>>(cur_d, pad_src, A8, s2, ssum,
                                            nullptr, G8);

    // ---- GCN layer: gather only (Wg folded into head via Wgf) -------------
    gcn_gather<<<WB, 256, 0, stream>>>(cur_d, pad_src, G8, GO_A, GO_B);

    // ---- pool + head ------------------------------------------------------
    pool_part<<<500, 128, 0, stream>>>(GO_A, GO_B, batch, pooled);
    head_kernel<<<1, 256, 0, stream>>>(pooled, gstart, Wgf, bgf, out);
}

// Round 11
// 252.190 us; speedup vs baseline: 1.0563x; 1.0307x over previous
//
#include <hip/hip_runtime.h>
#include <hip/hip_fp16.h>
#include <hip/hip_fp8.h>
#include <math.h>

#define NN 40000      // nodes
#define NE 640000     // raw edges
#define ET 680000     // edges + self loops
#define CH 128
#define OC 16
#define NG 64
#define NQ (ET/4)     // 170000 edge quads
#define CAP 48        // padded-CSR capacity per node (deg ~ Poisson(17))
#define NFILLB 665    // one block per 256 quads (unbucketed single pass)
#define NGEMMB 625    // 64-row tiles (full 128 cols internal)
#define NBLK1 (2*NGEMMB + (NFILLB - NGEMMB))   // 1290: pairwise interleave + tail
#define NSPLIT 20000  // gcn-out row split (pool block boundary: 20000/40=500)

typedef _Float16 h8 __attribute__((ext_vector_type(8)));
typedef float    f4 __attribute__((ext_vector_type(4)));
typedef float    f2 __attribute__((ext_vector_type(2)));

// ---- fp8 e4m3 conversions: HARDWARE path (v_cvt_pk_*_fp8, OCP on gfx950) --
#if __has_builtin(__builtin_amdgcn_cvt_pk_f32_fp8) && __has_builtin(__builtin_amdgcn_cvt_pk_fp8_f32)
#define FP8_HW 1
#else
#define FP8_HW 0
#endif

__device__ __forceinline__ float2 fp8x2_to_f32_sw(unsigned short v) {
    __hip_fp8_e4m3 a, b;
    a.__x = (__hip_fp8_storage_t)(v & 0xff);
    b.__x = (__hip_fp8_storage_t)(v >> 8);
    return make_float2((float)a, (float)b);
}

__device__ __forceinline__ unsigned char f32_to_fp8(float f) {
#if FP8_HW
    return (unsigned char)(__builtin_amdgcn_cvt_pk_fp8_f32(f, f, 0, false) & 0xff);
#else
    __hip_fp8_e4m3 t(f);
    return (unsigned char)t.__x;
#endif
}

// decode 8 fp8 bytes (uint2) and accumulate a[k] += val[k]*w
__device__ __forceinline__ void decode_fma8(uint2 v, float w, float* a) {
#if FP8_HW
    f2 p0 = __builtin_amdgcn_cvt_pk_f32_fp8((int)v.x, false);
    f2 p1 = __builtin_amdgcn_cvt_pk_f32_fp8((int)v.x, true);
    f2 p2 = __builtin_amdgcn_cvt_pk_f32_fp8((int)v.y, false);
    f2 p3 = __builtin_amdgcn_cvt_pk_f32_fp8((int)v.y, true);
    a[0] += p0[0] * w; a[1] += p0[1] * w;
    a[2] += p1[0] * w; a[3] += p1[1] * w;
    a[4] += p2[0] * w; a[5] += p2[1] * w;
    a[6] += p3[0] * w; a[7] += p3[1] * w;
#else
    float2 p0 = fp8x2_to_f32_sw((unsigned short)(v.x & 0xffff));
    float2 p1 = fp8x2_to_f32_sw((unsigned short)(v.x >> 16));
    float2 p2 = fp8x2_to_f32_sw((unsigned short)(v.y & 0xffff));
    float2 p3 = fp8x2_to_f32_sw((unsigned short)(v.y >> 16));
    a[0] += p0.x * w; a[1] += p0.y * w;
    a[2] += p1.x * w; a[3] += p1.y * w;
    a[4] += p2.x * w; a[5] += p2.y * w;
    a[6] += p3.x * w; a[7] += p3.y * w;
#endif
}

// pack 4 f32 (relu'd) into 4 fp8 bytes of a uint
__device__ __forceinline__ unsigned pack_fp8x4_relu(float a0, float a1,
                                                    float a2, float a3) {
#if FP8_HW
    int w = __builtin_amdgcn_cvt_pk_fp8_f32(fmaxf(a0, 0.f), fmaxf(a1, 0.f), 0, false);
    w = __builtin_amdgcn_cvt_pk_fp8_f32(fmaxf(a2, 0.f), fmaxf(a3, 0.f), w, true);
    return (unsigned)w;
#else
    return (unsigned)f32_to_fp8(fmaxf(a0, 0.f))
         | ((unsigned)f32_to_fp8(fmaxf(a1, 0.f)) << 8)
         | ((unsigned)f32_to_fp8(fmaxf(a2, 0.f)) << 16)
         | ((unsigned)f32_to_fp8(fmaxf(a3, 0.f)) << 24);
#endif
}

// ---- prep: zero scratch + graph bounds + W->fp16 transposed + Wg folding --
// Layer-3 algebra: gather/pool/Wg commute (all linear), so Wg is folded into
// the head: Wgf = Wg@Wfc [128x16], bgf = bg@Wfc + bfc [16]. gemm_k3 deleted.
__global__ __launch_bounds__(256)
void prep(const int* __restrict__ batch, int* __restrict__ gstart,
          int* __restrict__ cur_d, int* __restrict__ cur_s,
          float* __restrict__ pooled,
          const float* __restrict__ W1, const float* __restrict__ W2,
          const float* __restrict__ Wg, const float* __restrict__ Wfc,
          const float* __restrict__ bg, const float* __restrict__ bfc,
          _Float16* __restrict__ Wt1, _Float16* __restrict__ Wt2,
          float* __restrict__ Wgf, float* __restrict__ bgf)
{
    int i = blockIdx.x * 256 + threadIdx.x;
    if (i < NN) {
        cur_d[i] = 0; cur_s[i] = 0;
        int b = batch[i];
        if (i == 0) { for (int g = 0; g <= b; ++g) gstart[g] = 0; }
        else { int pb = batch[i - 1]; for (int g = pb + 1; g <= b; ++g) gstart[g] = i; }
        if (i == NN - 1) { for (int g = b + 1; g <= NG; ++g) gstart[g] = NN; }
    }
    if (i < NG * CH) pooled[i] = 0.f;
    if (i < CH * CH) {
        int k = i >> 7, n = i & 127;          // coalesced read W[k][n]
        Wt1[n * CH + k] = (_Float16)W1[i];
        Wt2[n * CH + k] = (_Float16)W2[i];
    }
    if (i < CH * OC) {                        // Wgf[k][o] = sum_c Wg[k][c]*Wfc[c][o]
        int k = i >> 4, o = i & 15;
        float acc = 0.f;
        for (int c = 0; c < CH; ++c)
            acc += Wg[k * CH + c] * Wfc[c * OC + o];
        Wgf[k * OC + o] = acc;
    }
    if (i >= CH * OC && i < CH * OC + OC) {   // bgf[o] = sum_c bg[c]*Wfc[c][o] + bfc[o]
        int o = i - CH * OC;
        float acc = bfc[o];
        for (int c = 0; c < CH; ++c)
            acc += bg[c] * Wfc[c * OC + o];
        bgf[o] = acc;
    }
}

// ---- stage Wt (global, [n][k] row-major) into LDS wt[128][136] ------------
__device__ __forceinline__
void stage_w(_Float16 (*wt)[136], const _Float16* __restrict__ Wt, int tid)
{
#pragma unroll
    for (int i = 0; i < 8; ++i) {
        int f = tid + i * 256;            // 0..2047 half8 chunks
        int n = f >> 4, c8 = f & 15;
        *(float4*)&wt[n][c8 * 8] = *(const float4*)(Wt + (size_t)n * CH + c8 * 8);
    }
}

// ---- MFMA body: 64 rows x 128 cols, K=128; xs and wt staged in LDS --------
// A-frag A[m][k=quad*8+j]; C/D col=lane&15, row=quad*4+reg (verified R6).
// b128 LDS reads process 16 lanes/phase -> (m,quad) mapping is 2-way/phase,
// conflict-free. Full row per block -> s[row] is a plain store (no atomic).
template<bool BIAS, bool ATTN>
__device__ __forceinline__
void mfma_body(_Float16 (*xs)[136], _Float16 (*wt)[136],
               const float* __restrict__ bias, const float* __restrict__ att,
               unsigned char* __restrict__ out8, float* __restrict__ s,
               int rb, int tid)
{
    const int wv = tid >> 6, lane = tid & 63;
    const int m = lane & 15, quad = lane >> 4;
    f4 acc[8] = {};
#pragma unroll
    for (int ks = 0; ks < 4; ++ks) {
        h8 a = *(const h8*)&xs[wv * 16 + m][ks * 32 + quad * 8];
#pragma unroll
        for (int t = 0; t < 8; ++t) {
            h8 b = *(const h8*)&wt[t * 16 + m][ks * 32 + quad * 8];
            acc[t] = __builtin_amdgcn_mfma_f32_16x16x32_f16(a, b, acc[t], 0, 0, 0);
        }
    }
    float pr[4] = {0.f, 0.f, 0.f, 0.f};
#pragma unroll
    for (int t = 0; t < 8; ++t) {
        int col = t * 16 + m;
        float bv = BIAS ? bias[col] : 0.f;
        float av = ATTN ? att[col] : 0.f;
#pragma unroll
        for (int r = 0; r < 4; ++r) {
            float o = acc[t][r] + bv;
            int row = rb + wv * 16 + quad * 4 + r;
            out8[(size_t)row * CH + col] = f32_to_fp8(o);
            if (ATTN) pr[r] += o * av;
        }
    }
    if (ATTN) {
#pragma unroll
        for (int r = 0; r < 4; ++r) {
            float p = pr[r];
            p += __shfl_xor(p, 1); p += __shfl_xor(p, 2);
            p += __shfl_xor(p, 4); p += __shfl_xor(p, 8);
            if (m == 0) s[rb + wv * 16 + quad * 4 + r] = p;  // full row here
        }
    }
}

// ---- fill body: unbucketed padded-CSR fill, 4 edges/thread, both sides ----
// Walled at coherent-op throughput: 2.72M atomic+scatter ops x ~32B sector
// ~= the measured 85MB WRITE_SIZE; four issue structures all land at
// 60-63us. Burst form kept (r10 best total).
__device__ __forceinline__
void fill_body(int fb, int tid, const int* __restrict__ ei,
               int* __restrict__ cur_d, int* __restrict__ cur_s,
               unsigned short* __restrict__ pad_src,
               unsigned short* __restrict__ pad_dst)
{
    int q = fb * 256 + tid;
    if (q >= NQ) return;
    int e0 = q * 4;
    int4 sv, dv;
    if (e0 < NE) {                          // quads never straddle NE (NE%4==0)
        sv = *(const int4*)(ei + e0);
        dv = *(const int4*)(ei + NE + e0);
    } else {
        int b = e0 - NE;
        sv = make_int4(b, b + 1, b + 2, b + 3);
        dv = sv;
    }
    const int* sc = (const int*)&sv;
    const int* dc = (const int*)&dv;
    int pd[4], ps[4];
#pragma unroll
    for (int u = 0; u < 4; ++u) pd[u] = atomicAdd(cur_d + dc[u], 1);
#pragma unroll
    for (int u = 0; u < 4; ++u) ps[u] = atomicAdd(cur_s + sc[u], 1);
#pragma unroll
    for (int u = 0; u < 4; ++u)
        if (pd[u] < CAP) pad_src[dc[u] * CAP + pd[u]] = (unsigned short)sc[u];
#pragma unroll
    for (int u = 0; u < 4; ++u)
        if (ps[u] < CAP) pad_dst[sc[u] * CAP + ps[u]] = (unsigned short)dc[u];
}

// ---- fused gemm1 + fill, pairwise-interleaved for co-residency ------------
__global__ __launch_bounds__(256)
void fill_gemm1(const float* __restrict__ x, const _Float16* __restrict__ Wt1,
                const float* __restrict__ b1, const float* __restrict__ att1,
                unsigned char* __restrict__ out8, float* __restrict__ s1,
                const int* __restrict__ ei, int* __restrict__ cur_d,
                int* __restrict__ cur_s, unsigned short* __restrict__ pad_src,
                unsigned short* __restrict__ pad_dst)
{
    __shared__ __attribute__((aligned(16))) _Float16 xs[64][136];
    __shared__ __attribute__((aligned(16))) _Float16 wt[128][136];
    int bid = blockIdx.x;
    if (bid < 2 * NGEMMB && (bid & 1) == 0) {
        int g = bid >> 1;
        int rb = g * 64, tid = threadIdx.x;
#pragma unroll
        for (int i = 0; i < 4; ++i) {
            int f = tid + i * 256;
            int r = f >> 4, c8 = f & 15;
            const float* p = x + (size_t)(rb + r) * CH + c8 * 8;
            float4 v0 = *(const float4*)p;
            float4 v1 = *(const float4*)(p + 4);
            __half2 h[4] = { __floats2half2_rn(v0.x, v0.y), __floats2half2_rn(v0.z, v0.w),
                             __floats2half2_rn(v1.x, v1.y), __floats2half2_rn(v1.z, v1.w) };
            *(float4*)&xs[r][c8 * 8] = *(float4*)h;
        }
        stage_w(wt, Wt1, tid);
        __syncthreads();
        mfma_body<true, true>(xs, wt, b1, att1, out8, s1, rb, tid);
        return;
    }
    int fb = (bid < 2 * NGEMMB) ? (bid >> 1) : (NGEMMB + (bid - 2 * NGEMMB));
    if (fb < NFILLB)
        fill_body(fb, threadIdx.x, ei, cur_d, cur_s, pad_src, pad_dst);
}

// ---- standalone gemm (layer 2): stage fp16 input + W, run MFMA ------------
template<bool RELU, bool BIAS, bool ATTN>
__global__ __launch_bounds__(256)
void gemm_k(const __half* __restrict__ in, const _Float16* __restrict__ Wt,
            const float* __restrict__ bias, const float* __restrict__ att,
            unsigned char* __restrict__ out8, float* __restrict__ s)
{
    __shared__ __attribute__((aligned(16))) _Float16 xs[64][136];
    __shared__ __attribute__((aligned(16))) _Float16 wt[128][136];
    const int tid = threadIdx.x;
    const int rb = blockIdx.x * 64;
#pragma unroll
    for (int i = 0; i < 4; ++i) {
        int f = tid + i * 256;            // 0..1023 half8 chunks
        int r = f >> 4, c8 = f & 15;
        float4 raw = *(const float4*)(in + (size_t)(rb + r) * CH + c8 * 8);
        if (RELU) {
            __half2* h2 = (__half2*)&raw;
#pragma unroll
            for (int u = 0; u < 4; ++u) {
                float2 fv = __half22float2(h2[u]);
                h2[u] = __floats2half2_rn(fmaxf(fv.x, 0.f), fmaxf(fv.y, 0.f));
            }
        }
        *(float4*)&xs[r][c8 * 8] = raw;
    }
    stage_w(wt, Wt, tid);
    __syncthreads();
    mfma_body<BIAS, ATTN>(xs, wt, bias, att, out8, s, rb, tid);
}

// ------- per-src-node softmax denom: 4 nodes/wave, 16 lanes each -----------
// Old form used 1 node/wave with lanes >= deg idle (deg~17 of 64 -> 73%
// waste). Now wave = 4 x 16-lane groups, each group strides its node's CSR
// row in steps of 16; shfl_xor 1/2/4/8 reduces within the group. 4x fewer
// waves (40000 -> 10000) = 4x fewer issue slots and pad-row transactions.
__global__ __launch_bounds__(256)
void softmax_stats(const int* __restrict__ cur_s,
                   const unsigned short* __restrict__ pad_dst,
                   const float* __restrict__ s, float* __restrict__ ssum)
{
    int wid = (blockIdx.x * 256 + threadIdx.x) >> 6;
    int lane = threadIdx.x & 63;
    int sub = lane >> 4, l16 = lane & 15;
    int node = wid * 4 + sub;
    if (node >= NN) return;
    int deg = min(cur_s[node], CAP);
    float si = s[node];
    float sum = 0.f;
    for (int j = l16; j < deg; j += 16) {
        int d = pad_dst[node * CAP + j];
        float t = si + s[d];
        t = t > 0.f ? t : 0.2f * t;
        sum += expf(t);
    }
    sum += __shfl_xor(sum, 1); sum += __shfl_xor(sum, 2);
    sum += __shfl_xor(sum, 4); sum += __shfl_xor(sum, 8);
    if (l16 == 0) ssum[node] = sum;
}

// ------- gather core: quad-edge scheme (one node per wave, max TLP) --------
// 4 quarters of 16 lanes; quarter q handles edges base+4u+q. Each lane reads
// uint2 = 8 fp8 (channels 8cl..8cl+7); combine via shfl_xor(16)+shfl_xor(32).
// Lanes >= deg: src=0,w=0 -> weight-0 row-0 reads.
// OM=0: fp16 row out. OM=1: relu + fp8 row out (feeds the layer-3 gather).
template<int OM>
__device__ __forceinline__
void gather_core(int node, int lane, int deg, int src, float w,
                 const unsigned char* __restrict__ h8p, void* __restrict__ outrow)
{
    int qtr = lane >> 4, cl = lane & 15;
    float a[8] = {};
    for (int base = 0; base < deg; base += 8) {
        uint2 v[2]; float wj[2];
#pragma unroll
        for (int u = 0; u < 2; ++u) {
            int e = base + 4 * u + qtr;           // e <= deg+7 <= 55 < 64
            int sj = __shfl(src, e);
            wj[u]  = __shfl(w, e);
            v[u] = ((const uint2*)(h8p + (size_t)sj * CH))[cl];
        }
#pragma unroll
        for (int u = 0; u < 2; ++u)
            decode_fma8(v[u], wj[u], a);
    }
#pragma unroll
    for (int k = 0; k < 8; ++k) {
        a[k] += __shfl_xor(a[k], 16);
        a[k] += __shfl_xor(a[k], 32);
    }
    if (qtr == 0) {
        if (OM == 0) {
            float4 st;
            ((__half2*)&st)[0] = __floats2half2_rn(a[0], a[1]);
            ((__half2*)&st)[1] = __floats2half2_rn(a[2], a[3]);
            ((__half2*)&st)[2] = __floats2half2_rn(a[4], a[5]);
            ((__half2*)&st)[3] = __floats2half2_rn(a[6], a[7]);
            ((float4*)outrow)[cl] = st;
        } else {
            unsigned lo = pack_fp8x4_relu(a[0], a[1], a[2], a[3]);
            unsigned hi = pack_fp8x4_relu(a[4], a[5], a[6], a[7]);
            ((uint2*)outrow)[cl] = make_uint2(lo, hi);
        }
    }
}

// ------- GT aggregation ----------------------------------------------------
// F8OUT=false (layer 1): fp16 out for gemm_k2. F8OUT=true (layer 2): relu'd
// fp8 out, consumed directly by gcn_gather (layer-3 gemm eliminated).
template<bool F8OUT>
__global__ __launch_bounds__(256)
void gt_gather(const int* __restrict__ cur_d,
               const unsigned short* __restrict__ pad_src,
               const unsigned char* __restrict__ h8p, const float* __restrict__ s,
               const float* __restrict__ ssum, __half* __restrict__ out16,
               unsigned char* __restrict__ o8)
{
    int node = (blockIdx.x * 256 + threadIdx.x) >> 6;
    int lane = threadIdx.x & 63;
    if (node >= NN) return;
    int deg = min(cur_d[node], CAP);
    float sd = s[node];
    int src = 0; float w = 0.f;
    if (lane < deg) {
        src = pad_src[node * CAP + lane];
        float t = sd + s[src];
        t = t > 0.f ? t : 0.2f * t;
        w = expf(t) / ssum[src];
    }
    if (F8OUT)
        gather_core<1>(node, lane, deg, src, w, h8p, o8 + (size_t)node * CH);
    else
        gather_core<0>(node, lane, deg, src, w, h8p, out16 + (size_t)node * CH);
}

// ------- GCN aggregation, inline dinv; split fp16 output (buffer reuse) ----
__global__ __launch_bounds__(256)
void gcn_gather(const int* __restrict__ cur_d,
                const unsigned short* __restrict__ pad_src,
                const unsigned char* __restrict__ h8p,
                __half* __restrict__ outA, __half* __restrict__ outB)
{
    int node = (blockIdx.x * 256 + threadIdx.x) >> 6;
    int lane = threadIdx.x & 63;
    if (node >= NN) return;
    int dn = cur_d[node];
    int deg = min(dn, CAP);
    float nu = rsqrtf((float)max(dn, 1));
    int src = 0; float w = 0.f;
    if (lane < deg) {
        src = pad_src[node * CAP + lane];
        w = rsqrtf((float)max(cur_d[src], 1)) * nu;
    }
    __half* row = (node < NSPLIT) ? outA + (size_t)node * CH
                                  : outB + (size_t)(node - NSPLIT) * CH;
    gather_core<0>(node, lane, deg, src, w, h8p, row);
}

// ---- pooling: 40-row chunks (1000 blocks) for 2x wave parallelism ---------
// Input rows split: [0,20000) in hA, [20000,40000) in hB; block 500 starts
// exactly at the split (20000/40). Extra per-block boundary atomics ~ +64K
// fire-and-forget floats: negligible vs the parallelism gain.
__global__ __launch_bounds__(128)
void pool_part(const __half* __restrict__ hA, const __half* __restrict__ hB,
               const int* __restrict__ batch, float* __restrict__ pooled)
{
    int ch = threadIdx.x;
    int start = blockIdx.x * 40;
    const __half* hp = (start < NSPLIT) ? hA + (size_t)start * CH
                                        : hB + (size_t)(start - NSPLIT) * CH;
    float acc = 0.f;
    int curg = batch[start];
    for (int base = start; base < start + 40; base += 8) {
        float vals[8]; int gs[8];
#pragma unroll
        for (int u = 0; u < 8; ++u)
            vals[u] = __half2float(hp[(size_t)(base - start + u) * CH + ch]);
#pragma unroll
        for (int u = 0; u < 8; ++u) gs[u] = batch[base + u];
#pragma unroll
        for (int u = 0; u < 8; ++u) {
            if (gs[u] != curg) {
                atomicAdd(pooled + (size_t)curg * CH + ch, acc);
                acc = 0.f; curg = gs[u];
            }
            acc += vals[u];
        }
    }
    atomicAdd(pooled + (size_t)curg * CH + ch, acc);
}

// ---- head: logits = (psum/cnt) @ Wgf + bgf; log_softmax -------------------
__global__ __launch_bounds__(256)
void head_kernel(const float* __restrict__ psum, const int* __restrict__ gstart,
                 const float* __restrict__ Wgf, const float* __restrict__ bgf,
                 float* __restrict__ out)
{
    __shared__ float lg[NG][OC];
    int tid = threadIdx.x;
#pragma unroll
    for (int i = 0; i < 4; ++i) {
        int f = tid + i * 256;        // 0..1023
        int g = f >> 4, o = f & 15;
        float cnt = fmaxf((float)(gstart[g + 1] - gstart[g]), 1.0f);
        float inv = 1.0f / cnt;
        float acc = bgf[o];
        for (int c = 0; c < CH; ++c)
            acc += psum[g * CH + c] * inv * Wgf[c * OC + o];
        lg[g][o] = acc;
    }
    __syncthreads();
    if (tid < NG) {
        float m = -1e30f;
#pragma unroll
        for (int o = 0; o < OC; ++o) m = fmaxf(m, lg[tid][o]);
        float sum = 0.f;
#pragma unroll
        for (int o = 0; o < OC; ++o) sum += expf(lg[tid][o] - m);
        float lse = m + logf(sum);
#pragma unroll
        for (int o = 0; o < OC; ++o) out[tid * OC + o] = lg[tid][o] - lse;
    }
}

extern "C" void kernel_launch(void* const* d_in, const int* in_sizes, int n_in,
                              void* d_out, int out_size, void* d_ws, size_t ws_size,
                              hipStream_t stream)
{
    const float* x     = (const float*)d_in[0];
    const int*   ei    = (const int*)d_in[1];
    const int*   batch = (const int*)d_in[2];
    const float* W1    = (const float*)d_in[3];
    const float* b1    = (const float*)d_in[4];
    const float* att1  = (const float*)d_in[5];
    const float* W2    = (const float*)d_in[6];
    const float* b2    = (const float*)d_in[7];
    const float* att2  = (const float*)d_in[8];
    const float* Wg    = (const float*)d_in[9];
    const float* bg    = (const float*)d_in[10];
    const float* Wfc   = (const float*)d_in[11];
    const float* bfc   = (const float*)d_in[12];
    float* out = (float*)d_out;

    const size_t NNCH = (size_t)NN * CH;
    __half* B16 = (__half*)d_ws;                       // [NN*CH] fp16 scratch
    unsigned char* A8 = (unsigned char*)(B16 + NNCH);  // [NN*CH] fp8 scratch
    // Layer-3 buffer reuse (x2 and h2 are dead at the point of each reuse):
    unsigned char* G8 = (unsigned char*)B16;           // relu(x3) fp8, 5.12 MB
    __half* GO_A = B16 + (size_t)NSPLIT * CH;          // gcn out rows 0..19999
    __half* GO_B = (__half*)A8;                        // gcn out rows 20000..39999
    _Float16* Wt1 = (_Float16*)(A8 + NNCH);            // [CH*CH]
    _Float16* Wt2 = Wt1 + CH * CH;
    float* Wgf    = (float*)(Wt2 + CH * CH);           // [CH*OC]
    float* bgf    = Wgf + CH * OC;                     // [OC]
    int*   cur_d  = (int*)(bgf + OC);                  // [NN]
    int*   cur_s  = cur_d + NN;                        // [NN]
    float* s1     = (float*)(cur_s + NN);              // [NN]
    float* s2     = s1 + NN;                           // [NN]
    float* ssum   = s2 + NN;                           // [NN]
    float* pooled = ssum + NN;                         // [NG*CH]
    int*   gstart = (int*)(pooled + NG * CH);          // [NG+1]
    unsigned short* pad_src = (unsigned short*)(gstart + NG + 1);  // [NN*CAP]
    unsigned short* pad_dst = pad_src + (size_t)NN * CAP;          // [NN*CAP]

    const int WB = NN / 4;                 // 10000 (wave-per-node gather grids)
    const int SB = NN / 16;                // 2500 (4-node-per-wave stats grid)

    prep<<<157, 256, 0, stream>>>(batch, gstart, cur_d, cur_s, pooled,
                                  W1, W2, Wg, Wfc, bg, bfc, Wt1, Wt2, Wgf, bgf);

    // ---- GT layer 1: gemm1 co-resident with CSR fill ----------------------
    fill_gemm1<<<NBLK1, 256, 0, stream>>>(
        x, Wt1, b1, att1, A8, s1, ei, cur_d, cur_s, pad_src, pad_dst);
    softmax_stats<<<SB, 256, 0, stream>>>(cur_s, pad_dst, s1, ssum);
    gt_gather<false><<<WB, 256, 0, stream>>>(cur_d, pad_src, A8, s1, ssum,
                                             B16, nullptr);

    // ---- GT layer 2 (relu folded into gemm input read) --------------------
    gemm_k<true, true, true><<<NGEMMB, 256, 0, stream>>>(
        B16, Wt2, b2, att2, A8, s2);
    softmax_stats<<<SB, 256, 0, stream>>>(cur_s, pad_dst, s2, ssum);
    gt_gather<true><<<WB, 256, 0, stream>>>(cur_d, pad_src, A8, s2, ssum,
                                            nullptr, G8);

    // ---- GCN layer: gather only (Wg folded into head via Wgf) -------------
    gcn_gather<<<WB, 256, 0, stream>>>(cur_d, pad_src, G8, GO_A, GO_B);

    // ---- pool + head ------------------------------------------------------
    pool_part<<<1000, 128, 0, stream>>>(GO_A, GO_B, batch, pooled);
    head_kernel<<<1, 256, 0, stream>>>(pooled, gstart, Wgf, bgf, out);
}